// Round 4
// baseline (696.590 us; speedup 1.0000x reference)
//
#include <hip/hip_runtime.h>

#define NN 100000
#define NE 1600000
#define NB 98    // ceil(NN/1024) — scan blocks AND node-buckets
#define NBK 98   // buckets of 1024 nodes
#define BSH 10   // bucket = dst >> 10

// ---------------- bucketed CSR build ----------------

__global__ void k_hist(const int* __restrict__ dst, int* __restrict__ bucketCnt) {
  __shared__ int lc[NBK];
  const int t = threadIdx.x;
  for (int i = t; i < NBK; i += 256) lc[i] = 0;
  __syncthreads();
  const int base = blockIdx.x * 4096;
#pragma unroll
  for (int q = 0; q < 16; q++) {
    int e = base + t + 256 * q;
    if (e < NE) atomicAdd(&lc[dst[e] >> BSH], 1);
  }
  __syncthreads();
  for (int i = t; i < NBK; i += 256)
    if (lc[i]) atomicAdd(&bucketCnt[i], lc[i]);
}

__global__ void k_scanb(const int* __restrict__ bucketCnt, int* __restrict__ bucketBase,
                        int* __restrict__ bucketCursor) {
  if (threadIdx.x == 0) {
    int run = 0;
    for (int i = 0; i < NBK; i++) {
      bucketBase[i] = run;
      bucketCursor[i] = run;
      run += bucketCnt[i];
    }
    bucketBase[NBK] = run;  // == NE
  }
}

// Partial sort of edges into 1024-node buckets: coalesced pair writes.
__global__ __launch_bounds__(256) void k_scatter(const int* __restrict__ src,
                                                 const int* __restrict__ dst,
                                                 int* __restrict__ bucketCursor,
                                                 unsigned long long* __restrict__ pairArr) {
  __shared__ int lcnt[NBK];
  __shared__ int lbase[NBK];
  __shared__ int lrank[NBK];
  __shared__ int bbase[NBK];
  __shared__ unsigned long long sorted[4096];
  __shared__ int target[4096];
  const int t = threadIdx.x;
  for (int i = t; i < NBK; i += 256) { lcnt[i] = 0; lrank[i] = 0; }
  __syncthreads();
  const int base = blockIdx.x * 4096;
  int rs[16], rd[16];
#pragma unroll
  for (int q = 0; q < 16; q++) {
    int e = base + t + 256 * q;
    rs[q] = (e < NE) ? src[e] : -1;
    rd[q] = (e < NE) ? dst[e] : -1;
    if (rd[q] >= 0) atomicAdd(&lcnt[rd[q] >> BSH], 1);
  }
  __syncthreads();
  if (t == 0) {
    int run = 0;
    for (int i = 0; i < NBK; i++) { lbase[i] = run; run += lcnt[i]; }
  }
  __syncthreads();
  if (t < NBK && lcnt[t] > 0) bbase[t] = atomicAdd(&bucketCursor[t], lcnt[t]);
  __syncthreads();
#pragma unroll
  for (int q = 0; q < 16; q++) {
    if (rd[q] >= 0) {
      int b = rd[q] >> BSH;
      int r = atomicAdd(&lrank[b], 1);
      int slot = lbase[b] + r;
      sorted[slot] = ((unsigned long long)(unsigned)rs[q] << 32) | (unsigned)rd[q];
      target[slot] = bbase[b] + r;
    }
  }
  __syncthreads();
  const int n = min(4096, NE - base);
  for (int s = t; s < n; s += 256) pairArr[target[s]] = sorted[s];
}

// One block per bucket: per-node counts via LDS atomics, plus dinv.
__global__ void k_cntdinv(const unsigned long long* __restrict__ pairArr,
                          const int* __restrict__ bucketBase,
                          int* __restrict__ cnt, float* __restrict__ dinv) {
  __shared__ int lc[1024];
  const int t = threadIdx.x;
  const int b = blockIdx.x;
  for (int i = t; i < 1024; i += 256) lc[i] = 0;
  __syncthreads();
  const int ebeg = bucketBase[b], eend = bucketBase[b + 1];
  const int n0 = b << BSH;
  for (int i = ebeg + t; i < eend; i += 256) {
    int d = (int)(unsigned)(pairArr[i] & 0xffffffffULL);
    atomicAdd(&lc[d - n0], 1);
  }
  __syncthreads();
  for (int i = t; i < 1024; i += 256) {
    int node = n0 + i;
    if (node < NN) {
      cnt[node] = lc[i];
      dinv[node] = rsqrtf(1.0f + (float)lc[i]);  // self-loop => deg >= 1
    }
  }
}

// One block per bucket: col writes confined to one ~64KB window, one XCD.
__global__ void k_csrfill(const unsigned long long* __restrict__ pairArr,
                          const int* __restrict__ bucketBase,
                          const int* __restrict__ rowptr,
                          int* __restrict__ col) {
  __shared__ int curs[1024];
  const int t = threadIdx.x;
  const int b = blockIdx.x;
  const int n0 = b << BSH;
  for (int i = t; i < 1024; i += 256) {
    int node = n0 + i;
    curs[i] = (node < NN) ? rowptr[node] : 0;
  }
  __syncthreads();
  const int ebeg = bucketBase[b], eend = bucketBase[b + 1];
  for (int i = ebeg + t; i < eend; i += 256) {
    unsigned long long p = pairArr[i];
    int d = (int)(unsigned)(p & 0xffffffffULL);
    int s = (int)(unsigned)(p >> 32);
    int pos = atomicAdd(&curs[d - n0], 1);
    col[pos] = s;
  }
}

// ---------------- rowptr scan ----------------

__global__ void k_scan1(const int* __restrict__ cnt, int* __restrict__ rowptr,
                        int* __restrict__ bsum) {
  __shared__ int sd[256];
  const int t = threadIdx.x;
  const int base = blockIdx.x * 1024 + t * 4;
  int v0 = (base + 0 < NN) ? cnt[base + 0] : 0;
  int v1 = (base + 1 < NN) ? cnt[base + 1] : 0;
  int v2 = (base + 2 < NN) ? cnt[base + 2] : 0;
  int v3 = (base + 3 < NN) ? cnt[base + 3] : 0;
  const int s = v0 + v1 + v2 + v3;
  sd[t] = s;
  __syncthreads();
  for (int off = 1; off < 256; off <<= 1) {
    int x = (t >= off) ? sd[t - off] : 0;
    __syncthreads();
    sd[t] += x;
    __syncthreads();
  }
  if (t == 255) bsum[blockIdx.x] = sd[255];
  int run = sd[t] - s;
  if (base + 0 < NN) rowptr[base + 0] = run; run += v0;
  if (base + 1 < NN) rowptr[base + 1] = run; run += v1;
  if (base + 2 < NN) rowptr[base + 2] = run; run += v2;
  if (base + 3 < NN) rowptr[base + 3] = run;
}

__global__ void k_scan2(int* bsum) {
  if (threadIdx.x == 0 && blockIdx.x == 0) {
    int run = 0;
    for (int i = 0; i < NB; i++) { int t = bsum[i]; bsum[i] = run; run += t; }
  }
}

__global__ void k_scan3(const int* __restrict__ bsum, int* __restrict__ rowptr) {
  int i = blockIdx.x * 256 + threadIdx.x;
  if (i < NN) rowptr[i] = rowptr[i] + bsum[i >> 10];
  if (i == 0) rowptr[NN] = NE;
}

// ---------------- dense transform: hs[r] = (X[r] @ W) * dinv[r] ----------------
// k-major LDS for X (ds_read_b128), W read straight from global (L1-resident
// 16 KB per K-chunk, 16-lane same-address broadcast). LDS pipe per k-step per
// wave: 2 b128 (~24 cyc) vs 128 cyc VALU -> VALU-bound.

template <int COUT>
__global__ __launch_bounds__(256) void k_gemm(const float* __restrict__ X,
                                              const float* __restrict__ W,
                                              const float* __restrict__ dinv,
                                              float* __restrict__ hs) {
  constexpr int CT = COUT / 8;       // col-thread groups (16 or 8)
  constexpr int RT = 256 / CT;       // row-thread groups (16 or 32)
  constexpr int ROWTILE = RT * 8;    // 128 or 256
  constexpr int KC = 32;
  constexpr int KIN = 128;
  constexpr int XSTR = ROWTILE + 4;  // keep 16B alignment of row starts
  __shared__ float xs[KC][XSTR];     // k-major: xs[k][row]

  const int tid = threadIdx.x;
  const int ct = tid % CT;
  const int rt = tid / CT;
  const int c0 = ct * 8;
  const int r0 = rt * 8;
  const long rowBase = (long)blockIdx.x * ROWTILE;

  float acc[8][8] = {};

  for (int kk = 0; kk < KIN; kk += KC) {
    // stage X chunk, transposing to k-major
    constexpr int XF4 = ROWTILE * KC / 4;  // 1024 or 2048 float4 loads
#pragma unroll
    for (int q = 0; q < XF4 / 256; q++) {
      int f = tid + 256 * q;
      int r = f >> 3;             // KC/4 = 8 float4 per row
      int kq = (f & 7) << 2;
      long gr = rowBase + r;
      if (gr > NN - 1) gr = NN - 1;
      const float4 xv = *reinterpret_cast<const float4*>(X + gr * KIN + kk + kq);
      xs[kq + 0][r] = xv.x;
      xs[kq + 1][r] = xv.y;
      xs[kq + 2][r] = xv.z;
      xs[kq + 3][r] = xv.w;
    }
    __syncthreads();
    const float* Wp = W + (long)kk * COUT + c0;
#pragma unroll 4
    for (int k = 0; k < KC; k++) {
      const float4 w0 = *reinterpret_cast<const float4*>(Wp + (long)k * COUT);
      const float4 w1 = *reinterpret_cast<const float4*>(Wp + (long)k * COUT + 4);
      const float4 x0 = *reinterpret_cast<const float4*>(&xs[k][r0]);
      const float4 x1 = *reinterpret_cast<const float4*>(&xs[k][r0 + 4]);
      float xr[8];
      xr[0] = x0.x; xr[1] = x0.y; xr[2] = x0.z; xr[3] = x0.w;
      xr[4] = x1.x; xr[5] = x1.y; xr[6] = x1.z; xr[7] = x1.w;
#pragma unroll
      for (int i = 0; i < 8; i++) {
        acc[i][0] = fmaf(xr[i], w0.x, acc[i][0]);
        acc[i][1] = fmaf(xr[i], w0.y, acc[i][1]);
        acc[i][2] = fmaf(xr[i], w0.z, acc[i][2]);
        acc[i][3] = fmaf(xr[i], w0.w, acc[i][3]);
        acc[i][4] = fmaf(xr[i], w1.x, acc[i][4]);
        acc[i][5] = fmaf(xr[i], w1.y, acc[i][5]);
        acc[i][6] = fmaf(xr[i], w1.z, acc[i][6]);
        acc[i][7] = fmaf(xr[i], w1.w, acc[i][7]);
      }
    }
    __syncthreads();
  }
#pragma unroll
  for (int i = 0; i < 8; i++) {
    long r = rowBase + r0 + i;
    if (r < NN) {
      float di = dinv[r];
      float4 o0 = make_float4(acc[i][0] * di, acc[i][1] * di,
                              acc[i][2] * di, acc[i][3] * di);
      float4 o1 = make_float4(acc[i][4] * di, acc[i][5] * di,
                              acc[i][6] * di, acc[i][7] * di);
      *reinterpret_cast<float4*>(hs + r * COUT + c0) = o0;
      *reinterpret_cast<float4*>(hs + r * COUT + c0 + 4) = o1;
    }
  }
}

// ---------------- aggregation (unchanged from round 3) ----------------

template <bool RELU>
__global__ __launch_bounds__(256) void k_agg128(const float* __restrict__ hs,
                                                const int* __restrict__ rowptr,
                                                const int* __restrict__ col,
                                                const float* __restrict__ dinv,
                                                const float* __restrict__ bias,
                                                float* __restrict__ out) {
  const int gid = blockIdx.x * 256 + threadIdx.x;
  const int node = gid >> 6;  // one wave per node
  if (node >= NN) return;
  const int lane = threadIdx.x & 63;
  const int half = lane >> 5;
  const int ch = (lane & 31) * 4;
  const int beg = rowptr[node];
  const int end = rowptr[node + 1];

  float4 acc;
  if (half == 0) {
    acc = *reinterpret_cast<const float4*>(hs + (long)node * 128 + ch);  // self
  } else {
    acc = make_float4(0.f, 0.f, 0.f, 0.f);
  }

  int j = beg;
  if (j + 8 <= end) {
    int c0 = col[j + 0 + half];
    int c1 = col[j + 2 + half];
    int c2 = col[j + 4 + half];
    int c3 = col[j + 6 + half];
    while (true) {
      const float4 v0 = *reinterpret_cast<const float4*>(hs + (long)c0 * 128 + ch);
      const float4 v1 = *reinterpret_cast<const float4*>(hs + (long)c1 * 128 + ch);
      const float4 v2 = *reinterpret_cast<const float4*>(hs + (long)c2 * 128 + ch);
      const float4 v3 = *reinterpret_cast<const float4*>(hs + (long)c3 * 128 + ch);
      j += 8;
      const bool more = (j + 8 <= end);
      int n0, n1, n2, n3;
      if (more) {
        n0 = col[j + 0 + half];
        n1 = col[j + 2 + half];
        n2 = col[j + 4 + half];
        n3 = col[j + 6 + half];
      }
      acc.x += (v0.x + v1.x) + (v2.x + v3.x);
      acc.y += (v0.y + v1.y) + (v2.y + v3.y);
      acc.z += (v0.z + v1.z) + (v2.z + v3.z);
      acc.w += (v0.w + v1.w) + (v2.w + v3.w);
      if (!more) break;
      c0 = n0; c1 = n1; c2 = n2; c3 = n3;
    }
  }
  for (; j + 2 <= end; j += 2) {
    int c = col[j + half];
    const float4 v = *reinterpret_cast<const float4*>(hs + (long)c * 128 + ch);
    acc.x += v.x; acc.y += v.y; acc.z += v.z; acc.w += v.w;
  }
  if (j < end && half == 0) {
    int c = col[j];
    const float4 v = *reinterpret_cast<const float4*>(hs + (long)c * 128 + ch);
    acc.x += v.x; acc.y += v.y; acc.z += v.z; acc.w += v.w;
  }

  acc.x += __shfl(acc.x, lane ^ 32);
  acc.y += __shfl(acc.y, lane ^ 32);
  acc.z += __shfl(acc.z, lane ^ 32);
  acc.w += __shfl(acc.w, lane ^ 32);

  if (half == 0) {
    const float di = dinv[node];
    const float4 b = *reinterpret_cast<const float4*>(bias + ch);
    float4 o;
    o.x = fmaf(acc.x, di, b.x);
    o.y = fmaf(acc.y, di, b.y);
    o.z = fmaf(acc.z, di, b.z);
    o.w = fmaf(acc.w, di, b.w);
    if (RELU) {
      o.x = fmaxf(o.x, 0.f); o.y = fmaxf(o.y, 0.f);
      o.z = fmaxf(o.z, 0.f); o.w = fmaxf(o.w, 0.f);
    }
    *reinterpret_cast<float4*>(out + (long)node * 128 + ch) = o;
  }
}

__global__ __launch_bounds__(256) void k_agg64(const float* __restrict__ hs,
                                               const int* __restrict__ rowptr,
                                               const int* __restrict__ col,
                                               const float* __restrict__ dinv,
                                               const float* __restrict__ bias,
                                               float* __restrict__ out) {
  const int gid = blockIdx.x * 256 + threadIdx.x;
  const int node = gid >> 6;
  if (node >= NN) return;
  const int lane = threadIdx.x & 63;
  const int quarter = lane >> 4;
  const int ch = (lane & 15) * 4;
  const int beg = rowptr[node];
  const int end = rowptr[node + 1];

  float4 acc;
  if (quarter == 0) {
    acc = *reinterpret_cast<const float4*>(hs + (long)node * 64 + ch);  // self
  } else {
    acc = make_float4(0.f, 0.f, 0.f, 0.f);
  }

  int j = beg;
  if (j + 8 <= end) {
    int c0 = col[j + 0 + quarter];
    int c1 = col[j + 4 + quarter];
    while (true) {
      const float4 v0 = *reinterpret_cast<const float4*>(hs + (long)c0 * 64 + ch);
      const float4 v1 = *reinterpret_cast<const float4*>(hs + (long)c1 * 64 + ch);
      j += 8;
      const bool more = (j + 8 <= end);
      int n0, n1;
      if (more) {
        n0 = col[j + 0 + quarter];
        n1 = col[j + 4 + quarter];
      }
      acc.x += v0.x + v1.x;
      acc.y += v0.y + v1.y;
      acc.z += v0.z + v1.z;
      acc.w += v0.w + v1.w;
      if (!more) break;
      c0 = n0; c1 = n1;
    }
  }
  for (; j + 4 <= end; j += 4) {
    int c = col[j + quarter];
    const float4 v = *reinterpret_cast<const float4*>(hs + (long)c * 64 + ch);
    acc.x += v.x; acc.y += v.y; acc.z += v.z; acc.w += v.w;
  }
  {
    const int r = end - j;
    if (quarter < r) {
      int c = col[j + quarter];
      const float4 v = *reinterpret_cast<const float4*>(hs + (long)c * 64 + ch);
      acc.x += v.x; acc.y += v.y; acc.z += v.z; acc.w += v.w;
    }
  }

  acc.x += __shfl(acc.x, lane ^ 32);
  acc.y += __shfl(acc.y, lane ^ 32);
  acc.z += __shfl(acc.z, lane ^ 32);
  acc.w += __shfl(acc.w, lane ^ 32);
  acc.x += __shfl(acc.x, lane ^ 16);
  acc.y += __shfl(acc.y, lane ^ 16);
  acc.z += __shfl(acc.z, lane ^ 16);
  acc.w += __shfl(acc.w, lane ^ 16);

  if (quarter == 0) {
    const float di = dinv[node];
    const float4 b = *reinterpret_cast<const float4*>(bias + ch);
    float4 o;
    o.x = fmaf(acc.x, di, b.x);
    o.y = fmaf(acc.y, di, b.y);
    o.z = fmaf(acc.z, di, b.z);
    o.w = fmaf(acc.w, di, b.w);
    *reinterpret_cast<float4*>(out + (long)node * 64 + ch) = o;
  }
}

// ---------------- launch ----------------

extern "C" void kernel_launch(void* const* d_in, const int* in_sizes, int n_in,
                              void* d_out, int out_size, void* d_ws, size_t ws_size,
                              hipStream_t stream) {
  const float* x  = (const float*)d_in[0];
  const int* ei   = (const int*)d_in[1];
  const float* W1 = (const float*)d_in[2];
  const float* b1 = (const float*)d_in[3];
  const float* W2 = (const float*)d_in[4];
  const float* b2 = (const float*)d_in[5];
  const float* W3 = (const float*)d_in[6];
  const float* b3 = (const float*)d_in[7];
  float* out = (float*)d_out;
  const int* srcp = ei;        // edge_index[0]
  const int* dstp = ei + NE;   // edge_index[1]

  char* wsb = (char*)d_ws;
  size_t off = 0;
  auto alloc = [&](size_t bytes) -> void* {
    void* p = wsb + off;
    off += (bytes + 255) & ~(size_t)255;
    return p;
  };
  float* hsA    = (float*)alloc((size_t)NN * 128 * 4);
  float* hB     = (float*)alloc((size_t)NN * 128 * 4);
  int*   col    = (int*)alloc((size_t)NE * 4);
  int*   rowptr = (int*)alloc((size_t)(NN + 1) * 4);
  int*   cnt    = (int*)alloc((size_t)NN * 4);
  float* dinv   = (float*)alloc((size_t)NN * 4);
  int*   bsum   = (int*)alloc((size_t)NB * 4);
  int*   bucketCnt    = (int*)alloc((size_t)NBK * 4);
  int*   bucketBase   = (int*)alloc((size_t)(NBK + 1) * 4);
  int*   bucketCursor = (int*)alloc((size_t)NBK * 4);
  unsigned long long* pairArr = (unsigned long long*)hsA;  // aliases hsA (build-only)
  (void)ws_size; (void)in_sizes; (void)n_in; (void)out_size;

  const int SCB = (NE + 4095) / 4096;

  hipMemsetAsync(bucketCnt, 0, (size_t)NBK * 4, stream);
  k_hist<<<SCB, 256, 0, stream>>>(dstp, bucketCnt);
  k_scanb<<<1, 64, 0, stream>>>(bucketCnt, bucketBase, bucketCursor);
  k_scatter<<<SCB, 256, 0, stream>>>(srcp, dstp, bucketCursor, pairArr);
  k_cntdinv<<<NBK, 256, 0, stream>>>(pairArr, bucketBase, cnt, dinv);
  k_scan1<<<NB, 256, 0, stream>>>(cnt, rowptr, bsum);
  k_scan2<<<1, 64, 0, stream>>>(bsum);
  k_scan3<<<(NN + 255) / 256, 256, 0, stream>>>(bsum, rowptr);
  k_csrfill<<<NBK, 256, 0, stream>>>(pairArr, bucketBase, rowptr, col);

  const int aggGrid = (NN * 64) / 256;  // 25000

  // layer 1
  k_gemm<128><<<(NN + 127) / 128, 256, 0, stream>>>(x, W1, dinv, hsA);
  k_agg128<true><<<aggGrid, 256, 0, stream>>>(hsA, rowptr, col, dinv, b1, hB);
  // layer 2
  k_gemm<128><<<(NN + 127) / 128, 256, 0, stream>>>(hB, W2, dinv, hsA);
  k_agg128<true><<<aggGrid, 256, 0, stream>>>(hsA, rowptr, col, dinv, b2, hB);
  // layer 3 (128 -> 64, no relu)
  k_gemm<64><<<(NN + 255) / 256, 256, 0, stream>>>(hB, W3, dinv, hsA);
  k_agg64<<<aggGrid, 256, 0, stream>>>(hsA, rowptr, col, dinv, b3, out);
}

// Round 5
// 502.800 us; speedup vs baseline: 1.3854x; 1.3854x over previous
//
#include <hip/hip_runtime.h>

#define NN 100000
#define NE 1600000
#define NB 98    // ceil(NN/1024) — scan blocks AND node-buckets
#define NBK 98   // buckets of 1024 nodes
#define BSH 10   // bucket = dst >> 10

// ---------------- bf16 helpers ----------------

__device__ __forceinline__ unsigned bfpack2(float a, float b) {
  unsigned ua = __float_as_uint(a); ua += 0x7FFF + ((ua >> 16) & 1);
  unsigned ub = __float_as_uint(b); ub += 0x7FFF + ((ub >> 16) & 1);
  return (ua >> 16) | (ub & 0xFFFF0000u);
}

__device__ __forceinline__ void acc8(const uint4 v, float* a) {
  a[0] += __uint_as_float(v.x << 16);
  a[1] += __uint_as_float(v.x & 0xFFFF0000u);
  a[2] += __uint_as_float(v.y << 16);
  a[3] += __uint_as_float(v.y & 0xFFFF0000u);
  a[4] += __uint_as_float(v.z << 16);
  a[5] += __uint_as_float(v.z & 0xFFFF0000u);
  a[6] += __uint_as_float(v.w << 16);
  a[7] += __uint_as_float(v.w & 0xFFFF0000u);
}

// ---------------- bucketed CSR build ----------------

__global__ void k_hist(const int* __restrict__ dst, int* __restrict__ bucketCnt) {
  __shared__ int lc[NBK];
  const int t = threadIdx.x;
  for (int i = t; i < NBK; i += 256) lc[i] = 0;
  __syncthreads();
  const int base = blockIdx.x * 4096;
#pragma unroll
  for (int q = 0; q < 16; q++) {
    int e = base + t + 256 * q;
    if (e < NE) atomicAdd(&lc[dst[e] >> BSH], 1);
  }
  __syncthreads();
  for (int i = t; i < NBK; i += 256)
    if (lc[i]) atomicAdd(&bucketCnt[i], lc[i]);
}

__global__ void k_scanb(const int* __restrict__ bucketCnt, int* __restrict__ bucketBase,
                        int* __restrict__ bucketCursor) {
  if (threadIdx.x == 0) {
    int run = 0;
    for (int i = 0; i < NBK; i++) {
      bucketBase[i] = run;
      bucketCursor[i] = run;
      run += bucketCnt[i];
    }
    bucketBase[NBK] = run;  // == NE
  }
}

__global__ __launch_bounds__(256) void k_scatter(const int* __restrict__ src,
                                                 const int* __restrict__ dst,
                                                 int* __restrict__ bucketCursor,
                                                 unsigned long long* __restrict__ pairArr) {
  __shared__ int lcnt[NBK];
  __shared__ int lbase[NBK];
  __shared__ int lrank[NBK];
  __shared__ int bbase[NBK];
  __shared__ unsigned long long sorted[4096];
  __shared__ int target[4096];
  const int t = threadIdx.x;
  for (int i = t; i < NBK; i += 256) { lcnt[i] = 0; lrank[i] = 0; }
  __syncthreads();
  const int base = blockIdx.x * 4096;
  int rs[16], rd[16];
#pragma unroll
  for (int q = 0; q < 16; q++) {
    int e = base + t + 256 * q;
    rs[q] = (e < NE) ? src[e] : -1;
    rd[q] = (e < NE) ? dst[e] : -1;
    if (rd[q] >= 0) atomicAdd(&lcnt[rd[q] >> BSH], 1);
  }
  __syncthreads();
  if (t == 0) {
    int run = 0;
    for (int i = 0; i < NBK; i++) { lbase[i] = run; run += lcnt[i]; }
  }
  __syncthreads();
  if (t < NBK && lcnt[t] > 0) bbase[t] = atomicAdd(&bucketCursor[t], lcnt[t]);
  __syncthreads();
#pragma unroll
  for (int q = 0; q < 16; q++) {
    if (rd[q] >= 0) {
      int b = rd[q] >> BSH;
      int r = atomicAdd(&lrank[b], 1);
      int slot = lbase[b] + r;
      sorted[slot] = ((unsigned long long)(unsigned)rs[q] << 32) | (unsigned)rd[q];
      target[slot] = bbase[b] + r;
    }
  }
  __syncthreads();
  const int n = min(4096, NE - base);
  for (int s = t; s < n; s += 256) pairArr[target[s]] = sorted[s];
}

__global__ void k_cntdinv(const unsigned long long* __restrict__ pairArr,
                          const int* __restrict__ bucketBase,
                          int* __restrict__ cnt, float* __restrict__ dinv) {
  __shared__ int lc[1024];
  const int t = threadIdx.x;
  const int b = blockIdx.x;
  for (int i = t; i < 1024; i += 256) lc[i] = 0;
  __syncthreads();
  const int ebeg = bucketBase[b], eend = bucketBase[b + 1];
  const int n0 = b << BSH;
  for (int i = ebeg + t; i < eend; i += 256) {
    int d = (int)(unsigned)(pairArr[i] & 0xffffffffULL);
    atomicAdd(&lc[d - n0], 1);
  }
  __syncthreads();
  for (int i = t; i < 1024; i += 256) {
    int node = n0 + i;
    if (node < NN) {
      cnt[node] = lc[i];
      dinv[node] = rsqrtf(1.0f + (float)lc[i]);  // self-loop => deg >= 1
    }
  }
}

__global__ void k_csrfill(const unsigned long long* __restrict__ pairArr,
                          const int* __restrict__ bucketBase,
                          const int* __restrict__ rowptr,
                          int* __restrict__ col) {
  __shared__ int curs[1024];
  const int t = threadIdx.x;
  const int b = blockIdx.x;
  const int n0 = b << BSH;
  for (int i = t; i < 1024; i += 256) {
    int node = n0 + i;
    curs[i] = (node < NN) ? rowptr[node] : 0;
  }
  __syncthreads();
  const int ebeg = bucketBase[b], eend = bucketBase[b + 1];
  for (int i = ebeg + t; i < eend; i += 256) {
    unsigned long long p = pairArr[i];
    int d = (int)(unsigned)(p & 0xffffffffULL);
    int s = (int)(unsigned)(p >> 32);
    int pos = atomicAdd(&curs[d - n0], 1);
    col[pos] = s;
  }
}

// ---------------- rowptr scan ----------------

__global__ void k_scan1(const int* __restrict__ cnt, int* __restrict__ rowptr,
                        int* __restrict__ bsum) {
  __shared__ int sd[256];
  const int t = threadIdx.x;
  const int base = blockIdx.x * 1024 + t * 4;
  int v0 = (base + 0 < NN) ? cnt[base + 0] : 0;
  int v1 = (base + 1 < NN) ? cnt[base + 1] : 0;
  int v2 = (base + 2 < NN) ? cnt[base + 2] : 0;
  int v3 = (base + 3 < NN) ? cnt[base + 3] : 0;
  const int s = v0 + v1 + v2 + v3;
  sd[t] = s;
  __syncthreads();
  for (int off = 1; off < 256; off <<= 1) {
    int x = (t >= off) ? sd[t - off] : 0;
    __syncthreads();
    sd[t] += x;
    __syncthreads();
  }
  if (t == 255) bsum[blockIdx.x] = sd[255];
  int run = sd[t] - s;
  if (base + 0 < NN) rowptr[base + 0] = run; run += v0;
  if (base + 1 < NN) rowptr[base + 1] = run; run += v1;
  if (base + 2 < NN) rowptr[base + 2] = run; run += v2;
  if (base + 3 < NN) rowptr[base + 3] = run;
}

__global__ void k_scan2(int* bsum) {
  if (threadIdx.x == 0 && blockIdx.x == 0) {
    int run = 0;
    for (int i = 0; i < NB; i++) { int t = bsum[i]; bsum[i] = run; run += t; }
  }
}

__global__ void k_scan3(const int* __restrict__ bsum, int* __restrict__ rowptr) {
  int i = blockIdx.x * 256 + threadIdx.x;
  if (i < NN) rowptr[i] = rowptr[i] + bsum[i >> 10];
  if (i == 0) rowptr[NN] = NE;
}

// ---------------- dense transform: hs[r] = bf16((X[r] @ W) * dinv[r]) ----------
// Round-3 structure (measured best): row-major xs (broadcast b32 reads),
// W staged in LDS (b128 reads). Epilogue packs bf16 (halves write traffic).

template <int COUT>
__global__ __launch_bounds__(256) void k_gemm(const float* __restrict__ X,
                                              const float* __restrict__ W,
                                              const float* __restrict__ dinv,
                                              unsigned short* __restrict__ hs) {
  constexpr int CT = COUT / 8;
  constexpr int RT = 256 / CT;
  constexpr int ROWTILE = RT * 8;
  constexpr int KC = 32;
  constexpr int KIN = 128;
  __shared__ float xs[ROWTILE][KC + 1];
  __shared__ float wsh[KC][COUT];

  const int tid = threadIdx.x;
  const int ct = tid % CT;
  const int rt = tid / CT;
  const int c0 = ct * 8;
  const long rowBase = (long)blockIdx.x * ROWTILE;

  float acc[8][8] = {};

  for (int kk = 0; kk < KIN; kk += KC) {
    constexpr int XF4 = ROWTILE * KC / 4;
#pragma unroll
    for (int q = 0; q < XF4 / 256; q++) {
      int f = tid + 256 * q;
      int r = f >> 3;
      int kq = (f & 7) << 2;
      long gr = rowBase + r;
      if (gr > NN - 1) gr = NN - 1;
      const float4 xv = *reinterpret_cast<const float4*>(X + gr * KIN + kk + kq);
      xs[r][kq + 0] = xv.x; xs[r][kq + 1] = xv.y;
      xs[r][kq + 2] = xv.z; xs[r][kq + 3] = xv.w;
    }
    constexpr int WF4 = KC * COUT / 4;
#pragma unroll
    for (int q = 0; q < WF4 / 256; q++) {
      int f = tid + 256 * q;
      int wr = f / (COUT / 4);
      int wc = (f % (COUT / 4)) * 4;
      *reinterpret_cast<float4*>(&wsh[wr][wc]) =
          *reinterpret_cast<const float4*>(W + (long)(kk + wr) * COUT + wc);
    }
    __syncthreads();
#pragma unroll 4
    for (int k = 0; k < KC; k++) {
      const float4 w0 = *reinterpret_cast<const float4*>(&wsh[k][c0]);
      const float4 w1 = *reinterpret_cast<const float4*>(&wsh[k][c0 + 4]);
#pragma unroll
      for (int i = 0; i < 8; i++) {
        const float xv = xs[rt * 8 + i][k];
        acc[i][0] = fmaf(xv, w0.x, acc[i][0]);
        acc[i][1] = fmaf(xv, w0.y, acc[i][1]);
        acc[i][2] = fmaf(xv, w0.z, acc[i][2]);
        acc[i][3] = fmaf(xv, w0.w, acc[i][3]);
        acc[i][4] = fmaf(xv, w1.x, acc[i][4]);
        acc[i][5] = fmaf(xv, w1.y, acc[i][5]);
        acc[i][6] = fmaf(xv, w1.z, acc[i][6]);
        acc[i][7] = fmaf(xv, w1.w, acc[i][7]);
      }
    }
    __syncthreads();
  }
#pragma unroll
  for (int i = 0; i < 8; i++) {
    long r = rowBase + rt * 8 + i;
    if (r < NN) {
      float di = dinv[r];
      uint4 o;
      o.x = bfpack2(acc[i][0] * di, acc[i][1] * di);
      o.y = bfpack2(acc[i][2] * di, acc[i][3] * di);
      o.z = bfpack2(acc[i][4] * di, acc[i][5] * di);
      o.w = bfpack2(acc[i][6] * di, acc[i][7] * di);
      *reinterpret_cast<uint4*>(hs + r * COUT + c0) = o;
    }
  }
}

// ---------------- aggregation (bf16 gather, fp32 accumulate/output) ----------
// 128-ch: quarter-wave (16 lanes x 16B) covers one 256B row; one load instr
// fetches FOUR rows. 64-ch: eighth-wave covers one 128B row; 8 rows/instr.

template <bool RELU>
__global__ __launch_bounds__(256) void k_agg128(const unsigned short* __restrict__ hs,
                                                const int* __restrict__ rowptr,
                                                const int* __restrict__ col,
                                                const float* __restrict__ dinv,
                                                const float* __restrict__ bias,
                                                float* __restrict__ out) {
  const int gid = blockIdx.x * 256 + threadIdx.x;
  const int node = gid >> 6;  // one wave per node
  if (node >= NN) return;
  const int lane = threadIdx.x & 63;
  const int q = lane >> 4;          // quarter 0..3
  const int chb = (lane & 15) * 8;  // 8 channels per lane
  const int beg = rowptr[node];
  const int end = rowptr[node + 1];

  float a[8] = {};
  if (q == 0) {  // self-loop contribution
    const uint4 v = *reinterpret_cast<const uint4*>(hs + (long)node * 128 + chb);
    acc8(v, a);
  }

  int j = beg;
  if (j + 8 <= end) {
    int c0 = col[j + q];
    int c1 = col[j + 4 + q];
    while (true) {
      const uint4 v0 = *reinterpret_cast<const uint4*>(hs + (long)c0 * 128 + chb);
      const uint4 v1 = *reinterpret_cast<const uint4*>(hs + (long)c1 * 128 + chb);
      j += 8;
      const bool more = (j + 8 <= end);
      int n0, n1;
      if (more) { n0 = col[j + q]; n1 = col[j + 4 + q]; }
      acc8(v0, a);
      acc8(v1, a);
      if (!more) break;
      c0 = n0; c1 = n1;
    }
  }
  for (; j + 4 <= end; j += 4) {
    int c = col[j + q];
    const uint4 v = *reinterpret_cast<const uint4*>(hs + (long)c * 128 + chb);
    acc8(v, a);
  }
  {
    const int r = end - j;  // 0..3
    if (q < r) {
      int c = col[j + q];
      const uint4 v = *reinterpret_cast<const uint4*>(hs + (long)c * 128 + chb);
      acc8(v, a);
    }
  }

  // combine four quarter-wave partials
#pragma unroll
  for (int i = 0; i < 8; i++) a[i] += __shfl(a[i], lane ^ 32);
#pragma unroll
  for (int i = 0; i < 8; i++) a[i] += __shfl(a[i], lane ^ 16);

  if (q == 0) {
    const float di = dinv[node];
    const float4 b0 = *reinterpret_cast<const float4*>(bias + chb);
    const float4 b1 = *reinterpret_cast<const float4*>(bias + chb + 4);
    float4 o0, o1;
    o0.x = fmaf(a[0], di, b0.x); o0.y = fmaf(a[1], di, b0.y);
    o0.z = fmaf(a[2], di, b0.z); o0.w = fmaf(a[3], di, b0.w);
    o1.x = fmaf(a[4], di, b1.x); o1.y = fmaf(a[5], di, b1.y);
    o1.z = fmaf(a[6], di, b1.z); o1.w = fmaf(a[7], di, b1.w);
    if (RELU) {
      o0.x = fmaxf(o0.x, 0.f); o0.y = fmaxf(o0.y, 0.f);
      o0.z = fmaxf(o0.z, 0.f); o0.w = fmaxf(o0.w, 0.f);
      o1.x = fmaxf(o1.x, 0.f); o1.y = fmaxf(o1.y, 0.f);
      o1.z = fmaxf(o1.z, 0.f); o1.w = fmaxf(o1.w, 0.f);
    }
    *reinterpret_cast<float4*>(out + (long)node * 128 + chb) = o0;
    *reinterpret_cast<float4*>(out + (long)node * 128 + chb + 4) = o1;
  }
}

__global__ __launch_bounds__(256) void k_agg64(const unsigned short* __restrict__ hs,
                                               const int* __restrict__ rowptr,
                                               const int* __restrict__ col,
                                               const float* __restrict__ dinv,
                                               const float* __restrict__ bias,
                                               float* __restrict__ out) {
  const int gid = blockIdx.x * 256 + threadIdx.x;
  const int node = gid >> 6;
  if (node >= NN) return;
  const int lane = threadIdx.x & 63;
  const int o8 = lane >> 3;        // eighth 0..7
  const int chb = (lane & 7) * 8;  // 8 channels per lane
  const int beg = rowptr[node];
  const int end = rowptr[node + 1];

  float a[8] = {};
  if (o8 == 0) {  // self
    const uint4 v = *reinterpret_cast<const uint4*>(hs + (long)node * 64 + chb);
    acc8(v, a);
  }

  int j = beg;
  if (j + 16 <= end) {
    int c0 = col[j + o8];
    int c1 = col[j + 8 + o8];
    while (true) {
      const uint4 v0 = *reinterpret_cast<const uint4*>(hs + (long)c0 * 64 + chb);
      const uint4 v1 = *reinterpret_cast<const uint4*>(hs + (long)c1 * 64 + chb);
      j += 16;
      const bool more = (j + 16 <= end);
      int n0, n1;
      if (more) { n0 = col[j + o8]; n1 = col[j + 8 + o8]; }
      acc8(v0, a);
      acc8(v1, a);
      if (!more) break;
      c0 = n0; c1 = n1;
    }
  }
  for (; j + 8 <= end; j += 8) {
    int c = col[j + o8];
    const uint4 v = *reinterpret_cast<const uint4*>(hs + (long)c * 64 + chb);
    acc8(v, a);
  }
  {
    const int r = end - j;  // 0..7
    if (o8 < r) {
      int c = col[j + o8];
      const uint4 v = *reinterpret_cast<const uint4*>(hs + (long)c * 64 + chb);
      acc8(v, a);
    }
  }

#pragma unroll
  for (int i = 0; i < 8; i++) a[i] += __shfl(a[i], lane ^ 32);
#pragma unroll
  for (int i = 0; i < 8; i++) a[i] += __shfl(a[i], lane ^ 16);
#pragma unroll
  for (int i = 0; i < 8; i++) a[i] += __shfl(a[i], lane ^ 8);

  if (o8 == 0) {
    const float di = dinv[node];
    const float4 b0 = *reinterpret_cast<const float4*>(bias + chb);
    const float4 b1 = *reinterpret_cast<const float4*>(bias + chb + 4);
    float4 r0, r1;
    r0.x = fmaf(a[0], di, b0.x); r0.y = fmaf(a[1], di, b0.y);
    r0.z = fmaf(a[2], di, b0.z); r0.w = fmaf(a[3], di, b0.w);
    r1.x = fmaf(a[4], di, b1.x); r1.y = fmaf(a[5], di, b1.y);
    r1.z = fmaf(a[6], di, b1.z); r1.w = fmaf(a[7], di, b1.w);
    *reinterpret_cast<float4*>(out + (long)node * 64 + chb) = r0;
    *reinterpret_cast<float4*>(out + (long)node * 64 + chb + 4) = r1;
  }
}

// ---------------- launch ----------------

extern "C" void kernel_launch(void* const* d_in, const int* in_sizes, int n_in,
                              void* d_out, int out_size, void* d_ws, size_t ws_size,
                              hipStream_t stream) {
  const float* x  = (const float*)d_in[0];
  const int* ei   = (const int*)d_in[1];
  const float* W1 = (const float*)d_in[2];
  const float* b1 = (const float*)d_in[3];
  const float* W2 = (const float*)d_in[4];
  const float* b2 = (const float*)d_in[5];
  const float* W3 = (const float*)d_in[6];
  const float* b3 = (const float*)d_in[7];
  float* out = (float*)d_out;
  const int* srcp = ei;        // edge_index[0]
  const int* dstp = ei + NE;   // edge_index[1]

  char* wsb = (char*)d_ws;
  size_t off = 0;
  auto alloc = [&](size_t bytes) -> void* {
    void* p = wsb + off;
    off += (bytes + 255) & ~(size_t)255;
    return p;
  };
  unsigned short* hsA = (unsigned short*)alloc((size_t)NN * 128 * 2);  // bf16 transform
  float* hB     = (float*)alloc((size_t)NN * 128 * 4);                 // fp32 activations
  int*   col    = (int*)alloc((size_t)NE * 4);
  int*   rowptr = (int*)alloc((size_t)(NN + 1) * 4);
  int*   cnt    = (int*)alloc((size_t)NN * 4);
  float* dinv   = (float*)alloc((size_t)NN * 4);
  int*   bsum   = (int*)alloc((size_t)NB * 4);
  int*   bucketCnt    = (int*)alloc((size_t)NBK * 4);
  int*   bucketBase   = (int*)alloc((size_t)(NBK + 1) * 4);
  int*   bucketCursor = (int*)alloc((size_t)NBK * 4);
  // pairArr (12.8 MB) aliases hsA (25.6 MB): only live during CSR build.
  unsigned long long* pairArr = (unsigned long long*)hsA;
  (void)ws_size; (void)in_sizes; (void)n_in; (void)out_size;

  const int SCB = (NE + 4095) / 4096;

  hipMemsetAsync(bucketCnt, 0, (size_t)NBK * 4, stream);
  k_hist<<<SCB, 256, 0, stream>>>(dstp, bucketCnt);
  k_scanb<<<1, 64, 0, stream>>>(bucketCnt, bucketBase, bucketCursor);
  k_scatter<<<SCB, 256, 0, stream>>>(srcp, dstp, bucketCursor, pairArr);
  k_cntdinv<<<NBK, 256, 0, stream>>>(pairArr, bucketBase, cnt, dinv);
  k_scan1<<<NB, 256, 0, stream>>>(cnt, rowptr, bsum);
  k_scan2<<<1, 64, 0, stream>>>(bsum);
  k_scan3<<<(NN + 255) / 256, 256, 0, stream>>>(bsum, rowptr);
  k_csrfill<<<NBK, 256, 0, stream>>>(pairArr, bucketBase, rowptr, col);

  const int aggGrid = (NN * 64) / 256;  // 25000

  // layer 1
  k_gemm<128><<<(NN + 127) / 128, 256, 0, stream>>>(x, W1, dinv, hsA);
  k_agg128<true><<<aggGrid, 256, 0, stream>>>(hsA, rowptr, col, dinv, b1, hB);
  // layer 2
  k_gemm<128><<<(NN + 127) / 128, 256, 0, stream>>>(hB, W2, dinv, hsA);
  k_agg128<true><<<aggGrid, 256, 0, stream>>>(hsA, rowptr, col, dinv, b2, hB);
  // layer 3 (128 -> 64, no relu)
  k_gemm<64><<<(NN + 255) / 256, 256, 0, stream>>>(hB, W3, dinv, hsA);
  k_agg64<<<aggGrid, 256, 0, stream>>>(hsA, rowptr, col, dinv, b3, out);
}

// Round 6
// 498.852 us; speedup vs baseline: 1.3964x; 1.0079x over previous
//
#include <hip/hip_runtime.h>

#define NN 100000
#define NE 1600000
#define NB 98    // ceil(NN/1024) — scan blocks AND node-buckets
#define NBK 98   // buckets of 1024 nodes
#define BSH 10   // bucket = dst >> 10

// ---------------- bf16 helpers ----------------

__device__ __forceinline__ unsigned bfpack2(float a, float b) {
  unsigned ua = __float_as_uint(a); ua += 0x7FFF + ((ua >> 16) & 1);
  unsigned ub = __float_as_uint(b); ub += 0x7FFF + ((ub >> 16) & 1);
  return (ua >> 16) | (ub & 0xFFFF0000u);
}

__device__ __forceinline__ void acc8(const uint4 v, float* a) {
  a[0] += __uint_as_float(v.x << 16);
  a[1] += __uint_as_float(v.x & 0xFFFF0000u);
  a[2] += __uint_as_float(v.y << 16);
  a[3] += __uint_as_float(v.y & 0xFFFF0000u);
  a[4] += __uint_as_float(v.z << 16);
  a[5] += __uint_as_float(v.z & 0xFFFF0000u);
  a[6] += __uint_as_float(v.w << 16);
  a[7] += __uint_as_float(v.w & 0xFFFF0000u);
}

// ---------------- bucketed CSR build ----------------

__global__ void k_hist(const int* __restrict__ dst, int* __restrict__ bucketCnt) {
  __shared__ int lc[NBK];
  const int t = threadIdx.x;
  for (int i = t; i < NBK; i += 256) lc[i] = 0;
  __syncthreads();
  const int base = blockIdx.x * 4096;
#pragma unroll
  for (int q = 0; q < 16; q++) {
    int e = base + t + 256 * q;
    if (e < NE) atomicAdd(&lc[dst[e] >> BSH], 1);
  }
  __syncthreads();
  for (int i = t; i < NBK; i += 256)
    if (lc[i]) atomicAdd(&bucketCnt[i], lc[i]);
}

__global__ void k_scanb(const int* __restrict__ bucketCnt, int* __restrict__ bucketBase,
                        int* __restrict__ bucketCursor) {
  if (threadIdx.x == 0) {
    int run = 0;
    for (int i = 0; i < NBK; i++) {
      bucketBase[i] = run;
      bucketCursor[i] = run;
      run += bucketCnt[i];
    }
    bucketBase[NBK] = run;  // == NE
  }
}

__global__ __launch_bounds__(256) void k_scatter(const int* __restrict__ src,
                                                 const int* __restrict__ dst,
                                                 int* __restrict__ bucketCursor,
                                                 unsigned long long* __restrict__ pairArr) {
  __shared__ int lcnt[NBK];
  __shared__ int lbase[NBK];
  __shared__ int lrank[NBK];
  __shared__ int bbase[NBK];
  __shared__ unsigned long long sorted[4096];
  __shared__ int target[4096];
  const int t = threadIdx.x;
  for (int i = t; i < NBK; i += 256) { lcnt[i] = 0; lrank[i] = 0; }
  __syncthreads();
  const int base = blockIdx.x * 4096;
  int rs[16], rd[16];
#pragma unroll
  for (int q = 0; q < 16; q++) {
    int e = base + t + 256 * q;
    rs[q] = (e < NE) ? src[e] : -1;
    rd[q] = (e < NE) ? dst[e] : -1;
    if (rd[q] >= 0) atomicAdd(&lcnt[rd[q] >> BSH], 1);
  }
  __syncthreads();
  if (t == 0) {
    int run = 0;
    for (int i = 0; i < NBK; i++) { lbase[i] = run; run += lcnt[i]; }
  }
  __syncthreads();
  if (t < NBK && lcnt[t] > 0) bbase[t] = atomicAdd(&bucketCursor[t], lcnt[t]);
  __syncthreads();
#pragma unroll
  for (int q = 0; q < 16; q++) {
    if (rd[q] >= 0) {
      int b = rd[q] >> BSH;
      int r = atomicAdd(&lrank[b], 1);
      int slot = lbase[b] + r;
      sorted[slot] = ((unsigned long long)(unsigned)rs[q] << 32) | (unsigned)rd[q];
      target[slot] = bbase[b] + r;
    }
  }
  __syncthreads();
  const int n = min(4096, NE - base);
  for (int s = t; s < n; s += 256) pairArr[target[s]] = sorted[s];
}

__global__ void k_cntdinv(const unsigned long long* __restrict__ pairArr,
                          const int* __restrict__ bucketBase,
                          int* __restrict__ cnt, float* __restrict__ dinv) {
  __shared__ int lc[1024];
  const int t = threadIdx.x;
  const int b = blockIdx.x;
  for (int i = t; i < 1024; i += 256) lc[i] = 0;
  __syncthreads();
  const int ebeg = bucketBase[b], eend = bucketBase[b + 1];
  const int n0 = b << BSH;
  for (int i = ebeg + t; i < eend; i += 256) {
    int d = (int)(unsigned)(pairArr[i] & 0xffffffffULL);
    atomicAdd(&lc[d - n0], 1);
  }
  __syncthreads();
  for (int i = t; i < 1024; i += 256) {
    int node = n0 + i;
    if (node < NN) {
      cnt[node] = lc[i];
      dinv[node] = rsqrtf(1.0f + (float)lc[i]);  // self-loop => deg >= 1
    }
  }
}

__global__ void k_csrfill(const unsigned long long* __restrict__ pairArr,
                          const int* __restrict__ bucketBase,
                          const int* __restrict__ rowptr,
                          int* __restrict__ col) {
  __shared__ int curs[1024];
  const int t = threadIdx.x;
  const int b = blockIdx.x;
  const int n0 = b << BSH;
  for (int i = t; i < 1024; i += 256) {
    int node = n0 + i;
    curs[i] = (node < NN) ? rowptr[node] : 0;
  }
  __syncthreads();
  const int ebeg = bucketBase[b], eend = bucketBase[b + 1];
  for (int i = ebeg + t; i < eend; i += 256) {
    unsigned long long p = pairArr[i];
    int d = (int)(unsigned)(p & 0xffffffffULL);
    int s = (int)(unsigned)(p >> 32);
    int pos = atomicAdd(&curs[d - n0], 1);
    col[pos] = s;
  }
}

// ---------------- rowptr scan ----------------

__global__ void k_scan1(const int* __restrict__ cnt, int* __restrict__ rowptr,
                        int* __restrict__ bsum) {
  __shared__ int sd[256];
  const int t = threadIdx.x;
  const int base = blockIdx.x * 1024 + t * 4;
  int v0 = (base + 0 < NN) ? cnt[base + 0] : 0;
  int v1 = (base + 1 < NN) ? cnt[base + 1] : 0;
  int v2 = (base + 2 < NN) ? cnt[base + 2] : 0;
  int v3 = (base + 3 < NN) ? cnt[base + 3] : 0;
  const int s = v0 + v1 + v2 + v3;
  sd[t] = s;
  __syncthreads();
  for (int off = 1; off < 256; off <<= 1) {
    int x = (t >= off) ? sd[t - off] : 0;
    __syncthreads();
    sd[t] += x;
    __syncthreads();
  }
  if (t == 255) bsum[blockIdx.x] = sd[255];
  int run = sd[t] - s;
  if (base + 0 < NN) rowptr[base + 0] = run; run += v0;
  if (base + 1 < NN) rowptr[base + 1] = run; run += v1;
  if (base + 2 < NN) rowptr[base + 2] = run; run += v2;
  if (base + 3 < NN) rowptr[base + 3] = run;
}

__global__ void k_scan2(int* bsum) {
  if (threadIdx.x == 0 && blockIdx.x == 0) {
    int run = 0;
    for (int i = 0; i < NB; i++) { int t = bsum[i]; bsum[i] = run; run += t; }
  }
}

__global__ void k_scan3(const int* __restrict__ bsum, int* __restrict__ rowptr) {
  int i = blockIdx.x * 256 + threadIdx.x;
  if (i < NN) rowptr[i] = rowptr[i] + bsum[i >> 10];
  if (i == 0) rowptr[NN] = NE;
}

// ---------------- dense transform: hs[r] = bf16((X[r] @ W) * dinv[r]) ----------
// k-major xs (2x ds_read_b128/thread-k, conflict-free: bank=4k+r0 distinct
// across the wave's 4 row-groups) + W staged in LDS (b128, 2-way aliased =
// free). Inner loop LDS: 48 cyc/wave-k vs 128 VALU cyc — was 70 (8x b32 + 2x
// b128) in round 3; round 4's W-from-global stalled on vmcnt in-loop.

template <int COUT>
__global__ __launch_bounds__(256) void k_gemm(const float* __restrict__ X,
                                              const float* __restrict__ W,
                                              const float* __restrict__ dinv,
                                              unsigned short* __restrict__ hs) {
  constexpr int CT = COUT / 8;       // col-thread groups (16 or 8)
  constexpr int RT = 256 / CT;       // row-thread groups (16 or 32)
  constexpr int ROWTILE = RT * 8;    // 128 or 256
  constexpr int KC = 32;
  constexpr int KIN = 128;
  constexpr int XSTR = ROWTILE + 4;  // k-row stride: keeps 16B alignment
  __shared__ float xs[KC][XSTR];     // k-major
  __shared__ float wsh[KC][COUT];

  const int tid = threadIdx.x;
  const int ct = tid % CT;
  const int rt = tid / CT;
  const int c0 = ct * 8;
  const int r0 = rt * 8;
  const long rowBase = (long)blockIdx.x * ROWTILE;

  float acc[8][8] = {};

  for (int kk = 0; kk < KIN; kk += KC) {
    // stage X chunk, transposed to k-major
    constexpr int XF4 = ROWTILE * KC / 4;
#pragma unroll
    for (int q = 0; q < XF4 / 256; q++) {
      int f = tid + 256 * q;
      int r = f >> 3;             // 8 float4 per row
      int kq = (f & 7) << 2;
      long gr = rowBase + r;
      if (gr > NN - 1) gr = NN - 1;
      const float4 xv = *reinterpret_cast<const float4*>(X + gr * KIN + kk + kq);
      xs[kq + 0][r] = xv.x;
      xs[kq + 1][r] = xv.y;
      xs[kq + 2][r] = xv.z;
      xs[kq + 3][r] = xv.w;
    }
    // stage W chunk
    constexpr int WF4 = KC * COUT / 4;
#pragma unroll
    for (int q = 0; q < WF4 / 256; q++) {
      int f = tid + 256 * q;
      int wr = f / (COUT / 4);
      int wc = (f % (COUT / 4)) * 4;
      *reinterpret_cast<float4*>(&wsh[wr][wc]) =
          *reinterpret_cast<const float4*>(W + (long)(kk + wr) * COUT + wc);
    }
    __syncthreads();
#pragma unroll 4
    for (int k = 0; k < KC; k++) {
      const float4 x0 = *reinterpret_cast<const float4*>(&xs[k][r0]);
      const float4 x1 = *reinterpret_cast<const float4*>(&xs[k][r0 + 4]);
      const float4 w0 = *reinterpret_cast<const float4*>(&wsh[k][c0]);
      const float4 w1 = *reinterpret_cast<const float4*>(&wsh[k][c0 + 4]);
      float xr[8];
      xr[0] = x0.x; xr[1] = x0.y; xr[2] = x0.z; xr[3] = x0.w;
      xr[4] = x1.x; xr[5] = x1.y; xr[6] = x1.z; xr[7] = x1.w;
#pragma unroll
      for (int i = 0; i < 8; i++) {
        acc[i][0] = fmaf(xr[i], w0.x, acc[i][0]);
        acc[i][1] = fmaf(xr[i], w0.y, acc[i][1]);
        acc[i][2] = fmaf(xr[i], w0.z, acc[i][2]);
        acc[i][3] = fmaf(xr[i], w0.w, acc[i][3]);
        acc[i][4] = fmaf(xr[i], w1.x, acc[i][4]);
        acc[i][5] = fmaf(xr[i], w1.y, acc[i][5]);
        acc[i][6] = fmaf(xr[i], w1.z, acc[i][6]);
        acc[i][7] = fmaf(xr[i], w1.w, acc[i][7]);
      }
    }
    __syncthreads();
  }
#pragma unroll
  for (int i = 0; i < 8; i++) {
    long r = rowBase + r0 + i;
    if (r < NN) {
      float di = dinv[r];
      uint4 o;
      o.x = bfpack2(acc[i][0] * di, acc[i][1] * di);
      o.y = bfpack2(acc[i][2] * di, acc[i][3] * di);
      o.z = bfpack2(acc[i][4] * di, acc[i][5] * di);
      o.w = bfpack2(acc[i][6] * di, acc[i][7] * di);
      *reinterpret_cast<uint4*>(hs + r * COUT + c0) = o;
    }
  }
}

// ---------------- aggregation (bf16 gather, fp32 accumulate/output) ----------

template <bool RELU>
__global__ __launch_bounds__(256) void k_agg128(const unsigned short* __restrict__ hs,
                                                const int* __restrict__ rowptr,
                                                const int* __restrict__ col,
                                                const float* __restrict__ dinv,
                                                const float* __restrict__ bias,
                                                float* __restrict__ out) {
  const int gid = blockIdx.x * 256 + threadIdx.x;
  const int node = gid >> 6;  // one wave per node
  if (node >= NN) return;
  const int lane = threadIdx.x & 63;
  const int q = lane >> 4;          // quarter 0..3
  const int chb = (lane & 15) * 8;  // 8 channels per lane
  const int beg = rowptr[node];
  const int end = rowptr[node + 1];

  float a[8] = {};
  if (q == 0) {  // self-loop contribution
    const uint4 v = *reinterpret_cast<const uint4*>(hs + (long)node * 128 + chb);
    acc8(v, a);
  }

  int j = beg;
  if (j + 8 <= end) {
    int c0 = col[j + q];
    int c1 = col[j + 4 + q];
    while (true) {
      const uint4 v0 = *reinterpret_cast<const uint4*>(hs + (long)c0 * 128 + chb);
      const uint4 v1 = *reinterpret_cast<const uint4*>(hs + (long)c1 * 128 + chb);
      j += 8;
      const bool more = (j + 8 <= end);
      int n0, n1;
      if (more) { n0 = col[j + q]; n1 = col[j + 4 + q]; }
      acc8(v0, a);
      acc8(v1, a);
      if (!more) break;
      c0 = n0; c1 = n1;
    }
  }
  for (; j + 4 <= end; j += 4) {
    int c = col[j + q];
    const uint4 v = *reinterpret_cast<const uint4*>(hs + (long)c * 128 + chb);
    acc8(v, a);
  }
  {
    const int r = end - j;  // 0..3
    if (q < r) {
      int c = col[j + q];
      const uint4 v = *reinterpret_cast<const uint4*>(hs + (long)c * 128 + chb);
      acc8(v, a);
    }
  }

#pragma unroll
  for (int i = 0; i < 8; i++) a[i] += __shfl(a[i], lane ^ 32);
#pragma unroll
  for (int i = 0; i < 8; i++) a[i] += __shfl(a[i], lane ^ 16);

  if (q == 0) {
    const float di = dinv[node];
    const float4 b0 = *reinterpret_cast<const float4*>(bias + chb);
    const float4 b1 = *reinterpret_cast<const float4*>(bias + chb + 4);
    float4 o0, o1;
    o0.x = fmaf(a[0], di, b0.x); o0.y = fmaf(a[1], di, b0.y);
    o0.z = fmaf(a[2], di, b0.z); o0.w = fmaf(a[3], di, b0.w);
    o1.x = fmaf(a[4], di, b1.x); o1.y = fmaf(a[5], di, b1.y);
    o1.z = fmaf(a[6], di, b1.z); o1.w = fmaf(a[7], di, b1.w);
    if (RELU) {
      o0.x = fmaxf(o0.x, 0.f); o0.y = fmaxf(o0.y, 0.f);
      o0.z = fmaxf(o0.z, 0.f); o0.w = fmaxf(o0.w, 0.f);
      o1.x = fmaxf(o1.x, 0.f); o1.y = fmaxf(o1.y, 0.f);
      o1.z = fmaxf(o1.z, 0.f); o1.w = fmaxf(o1.w, 0.f);
    }
    *reinterpret_cast<float4*>(out + (long)node * 128 + chb) = o0;
    *reinterpret_cast<float4*>(out + (long)node * 128 + chb + 4) = o1;
  }
}

__global__ __launch_bounds__(256) void k_agg64(const unsigned short* __restrict__ hs,
                                               const int* __restrict__ rowptr,
                                               const int* __restrict__ col,
                                               const float* __restrict__ dinv,
                                               const float* __restrict__ bias,
                                               float* __restrict__ out) {
  const int gid = blockIdx.x * 256 + threadIdx.x;
  const int node = gid >> 6;
  if (node >= NN) return;
  const int lane = threadIdx.x & 63;
  const int o8 = lane >> 3;        // eighth 0..7
  const int chb = (lane & 7) * 8;  // 8 channels per lane
  const int beg = rowptr[node];
  const int end = rowptr[node + 1];

  float a[8] = {};
  if (o8 == 0) {  // self
    const uint4 v = *reinterpret_cast<const uint4*>(hs + (long)node * 64 + chb);
    acc8(v, a);
  }

  int j = beg;
  if (j + 16 <= end) {
    int c0 = col[j + o8];
    int c1 = col[j + 8 + o8];
    while (true) {
      const uint4 v0 = *reinterpret_cast<const uint4*>(hs + (long)c0 * 64 + chb);
      const uint4 v1 = *reinterpret_cast<const uint4*>(hs + (long)c1 * 64 + chb);
      j += 16;
      const bool more = (j + 16 <= end);
      int n0, n1;
      if (more) { n0 = col[j + o8]; n1 = col[j + 8 + o8]; }
      acc8(v0, a);
      acc8(v1, a);
      if (!more) break;
      c0 = n0; c1 = n1;
    }
  }
  for (; j + 8 <= end; j += 8) {
    int c = col[j + o8];
    const uint4 v = *reinterpret_cast<const uint4*>(hs + (long)c * 64 + chb);
    acc8(v, a);
  }
  {
    const int r = end - j;  // 0..7
    if (o8 < r) {
      int c = col[j + o8];
      const uint4 v = *reinterpret_cast<const uint4*>(hs + (long)c * 64 + chb);
      acc8(v, a);
    }
  }

#pragma unroll
  for (int i = 0; i < 8; i++) a[i] += __shfl(a[i], lane ^ 32);
#pragma unroll
  for (int i = 0; i < 8; i++) a[i] += __shfl(a[i], lane ^ 16);
#pragma unroll
  for (int i = 0; i < 8; i++) a[i] += __shfl(a[i], lane ^ 8);

  if (o8 == 0) {
    const float di = dinv[node];
    const float4 b0 = *reinterpret_cast<const float4*>(bias + chb);
    const float4 b1 = *reinterpret_cast<const float4*>(bias + chb + 4);
    float4 r0, r1;
    r0.x = fmaf(a[0], di, b0.x); r0.y = fmaf(a[1], di, b0.y);
    r0.z = fmaf(a[2], di, b0.z); r0.w = fmaf(a[3], di, b0.w);
    r1.x = fmaf(a[4], di, b1.x); r1.y = fmaf(a[5], di, b1.y);
    r1.z = fmaf(a[6], di, b1.z); r1.w = fmaf(a[7], di, b1.w);
    *reinterpret_cast<float4*>(out + (long)node * 64 + chb) = r0;
    *reinterpret_cast<float4*>(out + (long)node * 64 + chb + 4) = r1;
  }
}

// ---------------- launch ----------------

extern "C" void kernel_launch(void* const* d_in, const int* in_sizes, int n_in,
                              void* d_out, int out_size, void* d_ws, size_t ws_size,
                              hipStream_t stream) {
  const float* x  = (const float*)d_in[0];
  const int* ei   = (const int*)d_in[1];
  const float* W1 = (const float*)d_in[2];
  const float* b1 = (const float*)d_in[3];
  const float* W2 = (const float*)d_in[4];
  const float* b2 = (const float*)d_in[5];
  const float* W3 = (const float*)d_in[6];
  const float* b3 = (const float*)d_in[7];
  float* out = (float*)d_out;
  const int* srcp = ei;        // edge_index[0]
  const int* dstp = ei + NE;   // edge_index[1]

  char* wsb = (char*)d_ws;
  size_t off = 0;
  auto alloc = [&](size_t bytes) -> void* {
    void* p = wsb + off;
    off += (bytes + 255) & ~(size_t)255;
    return p;
  };
  unsigned short* hsA = (unsigned short*)alloc((size_t)NN * 128 * 2);  // bf16 transform
  float* hB     = (float*)alloc((size_t)NN * 128 * 4);                 // fp32 activations
  int*   col    = (int*)alloc((size_t)NE * 4);
  int*   rowptr = (int*)alloc((size_t)(NN + 1) * 4);
  int*   cnt    = (int*)alloc((size_t)NN * 4);
  float* dinv   = (float*)alloc((size_t)NN * 4);
  int*   bsum   = (int*)alloc((size_t)NB * 4);
  int*   bucketCnt    = (int*)alloc((size_t)NBK * 4);
  int*   bucketBase   = (int*)alloc((size_t)(NBK + 1) * 4);
  int*   bucketCursor = (int*)alloc((size_t)NBK * 4);
  // pairArr (12.8 MB) aliases hsA (25.6 MB): only live during CSR build.
  unsigned long long* pairArr = (unsigned long long*)hsA;
  (void)ws_size; (void)in_sizes; (void)n_in; (void)out_size;

  const int SCB = (NE + 4095) / 4096;

  hipMemsetAsync(bucketCnt, 0, (size_t)NBK * 4, stream);
  k_hist<<<SCB, 256, 0, stream>>>(dstp, bucketCnt);
  k_scanb<<<1, 64, 0, stream>>>(bucketCnt, bucketBase, bucketCursor);
  k_scatter<<<SCB, 256, 0, stream>>>(srcp, dstp, bucketCursor, pairArr);
  k_cntdinv<<<NBK, 256, 0, stream>>>(pairArr, bucketBase, cnt, dinv);
  k_scan1<<<NB, 256, 0, stream>>>(cnt, rowptr, bsum);
  k_scan2<<<1, 64, 0, stream>>>(bsum);
  k_scan3<<<(NN + 255) / 256, 256, 0, stream>>>(bsum, rowptr);
  k_csrfill<<<NBK, 256, 0, stream>>>(pairArr, bucketBase, rowptr, col);

  const int aggGrid = (NN * 64) / 256;  // 25000

  // layer 1
  k_gemm<128><<<(NN + 127) / 128, 256, 0, stream>>>(x, W1, dinv, hsA);
  k_agg128<true><<<aggGrid, 256, 0, stream>>>(hsA, rowptr, col, dinv, b1, hB);
  // layer 2
  k_gemm<128><<<(NN + 127) / 128, 256, 0, stream>>>(hB, W2, dinv, hsA);
  k_agg128<true><<<aggGrid, 256, 0, stream>>>(hsA, rowptr, col, dinv, b2, hB);
  // layer 3 (128 -> 64, no relu)
  k_gemm<64><<<(NN + 255) / 256, 256, 0, stream>>>(hB, W3, dinv, hsA);
  k_agg64<<<aggGrid, 256, 0, stream>>>(hsA, rowptr, col, dinv, b3, out);
}

// Round 7
// 467.824 us; speedup vs baseline: 1.4890x; 1.0663x over previous
//
#include <hip/hip_runtime.h>

#define NN 100000
#define NE 1600000
#define NB 98    // ceil(NN/1024) — scan blocks AND node-buckets
#define NBK 98   // buckets of 1024 nodes
#define BSH 10   // bucket = dst >> 10
#define MPAD 100096  // NN padded to 128-row tiles (782*128)

typedef unsigned short ushortT;
using sh8 = __attribute__((ext_vector_type(8))) short;   // 8 bf16 (4 VGPR) MFMA frag
using f4  = __attribute__((ext_vector_type(4))) float;   // MFMA accumulator

// ---------------- bf16 helpers ----------------

__device__ __forceinline__ unsigned short bfr(float f) {
  unsigned u = __float_as_uint(f);
  u += 0x7FFF + ((u >> 16) & 1);
  return (unsigned short)(u >> 16);
}
__device__ __forceinline__ float bf2f(unsigned short h) {
  return __uint_as_float(((unsigned)h) << 16);
}
// round a,b to bf16-hi, residual to bf16-lo; pack pairs into uints
__device__ __forceinline__ void split2(float a, float b, unsigned& H, unsigned& L) {
  unsigned short ha = bfr(a), hb = bfr(b);
  H = (unsigned)ha | ((unsigned)hb << 16);
  L = (unsigned)bfr(a - bf2f(ha)) | ((unsigned)bfr(b - bf2f(hb)) << 16);
}
__device__ __forceinline__ void acc8(const uint4 v, float* a) {
  a[0] += __uint_as_float(v.x << 16);
  a[1] += __uint_as_float(v.x & 0xFFFF0000u);
  a[2] += __uint_as_float(v.y << 16);
  a[3] += __uint_as_float(v.y & 0xFFFF0000u);
  a[4] += __uint_as_float(v.z << 16);
  a[5] += __uint_as_float(v.z & 0xFFFF0000u);
  a[6] += __uint_as_float(v.w << 16);
  a[7] += __uint_as_float(v.w & 0xFFFF0000u);
}

// ---------------- bucketed CSR build ----------------

__global__ void k_hist(const int* __restrict__ dst, int* __restrict__ bucketCnt) {
  __shared__ int lc[NBK];
  const int t = threadIdx.x;
  for (int i = t; i < NBK; i += 256) lc[i] = 0;
  __syncthreads();
  const int base = blockIdx.x * 4096;
#pragma unroll
  for (int q = 0; q < 16; q++) {
    int e = base + t + 256 * q;
    if (e < NE) atomicAdd(&lc[dst[e] >> BSH], 1);
  }
  __syncthreads();
  for (int i = t; i < NBK; i += 256)
    if (lc[i]) atomicAdd(&bucketCnt[i], lc[i]);
}

__global__ void k_scanb(const int* __restrict__ bucketCnt, int* __restrict__ bucketBase,
                        int* __restrict__ bucketCursor) {
  if (threadIdx.x == 0) {
    int run = 0;
    for (int i = 0; i < NBK; i++) {
      bucketBase[i] = run;
      bucketCursor[i] = run;
      run += bucketCnt[i];
    }
    bucketBase[NBK] = run;  // == NE
  }
}

__global__ __launch_bounds__(256) void k_scatter(const int* __restrict__ src,
                                                 const int* __restrict__ dst,
                                                 int* __restrict__ bucketCursor,
                                                 unsigned long long* __restrict__ pairArr) {
  __shared__ int lcnt[NBK];
  __shared__ int lbase[NBK];
  __shared__ int lrank[NBK];
  __shared__ int bbase[NBK];
  __shared__ unsigned long long sorted[4096];
  __shared__ int target[4096];
  const int t = threadIdx.x;
  for (int i = t; i < NBK; i += 256) { lcnt[i] = 0; lrank[i] = 0; }
  __syncthreads();
  const int base = blockIdx.x * 4096;
  int rs[16], rd[16];
#pragma unroll
  for (int q = 0; q < 16; q++) {
    int e = base + t + 256 * q;
    rs[q] = (e < NE) ? src[e] : -1;
    rd[q] = (e < NE) ? dst[e] : -1;
    if (rd[q] >= 0) atomicAdd(&lcnt[rd[q] >> BSH], 1);
  }
  __syncthreads();
  if (t == 0) {
    int run = 0;
    for (int i = 0; i < NBK; i++) { lbase[i] = run; run += lcnt[i]; }
  }
  __syncthreads();
  if (t < NBK && lcnt[t] > 0) bbase[t] = atomicAdd(&bucketCursor[t], lcnt[t]);
  __syncthreads();
#pragma unroll
  for (int q = 0; q < 16; q++) {
    if (rd[q] >= 0) {
      int b = rd[q] >> BSH;
      int r = atomicAdd(&lrank[b], 1);
      int slot = lbase[b] + r;
      sorted[slot] = ((unsigned long long)(unsigned)rs[q] << 32) | (unsigned)rd[q];
      target[slot] = bbase[b] + r;
    }
  }
  __syncthreads();
  const int n = min(4096, NE - base);
  for (int s = t; s < n; s += 256) pairArr[target[s]] = sorted[s];
}

__global__ void k_cntdinv(const unsigned long long* __restrict__ pairArr,
                          const int* __restrict__ bucketBase,
                          int* __restrict__ cnt, float* __restrict__ dinv) {
  __shared__ int lc[1024];
  const int t = threadIdx.x;
  const int b = blockIdx.x;
  for (int i = t; i < 1024; i += 256) lc[i] = 0;
  __syncthreads();
  const int ebeg = bucketBase[b], eend = bucketBase[b + 1];
  const int n0 = b << BSH;
  for (int i = ebeg + t; i < eend; i += 256) {
    int d = (int)(unsigned)(pairArr[i] & 0xffffffffULL);
    atomicAdd(&lc[d - n0], 1);
  }
  __syncthreads();
  for (int i = t; i < 1024; i += 256) {
    int node = n0 + i;
    if (node < NN) {
      cnt[node] = lc[i];
      dinv[node] = rsqrtf(1.0f + (float)lc[i]);  // self-loop => deg >= 1
    }
  }
}

__global__ void k_csrfill(const unsigned long long* __restrict__ pairArr,
                          const int* __restrict__ bucketBase,
                          const int* __restrict__ rowptr,
                          int* __restrict__ col) {
  __shared__ int curs[1024];
  const int t = threadIdx.x;
  const int b = blockIdx.x;
  const int n0 = b << BSH;
  for (int i = t; i < 1024; i += 256) {
    int node = n0 + i;
    curs[i] = (node < NN) ? rowptr[node] : 0;
  }
  __syncthreads();
  const int ebeg = bucketBase[b], eend = bucketBase[b + 1];
  for (int i = ebeg + t; i < eend; i += 256) {
    unsigned long long p = pairArr[i];
    int d = (int)(unsigned)(p & 0xffffffffULL);
    int s = (int)(unsigned)(p >> 32);
    int pos = atomicAdd(&curs[d - n0], 1);
    col[pos] = s;
  }
}

// ---------------- rowptr scan ----------------

__global__ void k_scan1(const int* __restrict__ cnt, int* __restrict__ rowptr,
                        int* __restrict__ bsum) {
  __shared__ int sd[256];
  const int t = threadIdx.x;
  const int base = blockIdx.x * 1024 + t * 4;
  int v0 = (base + 0 < NN) ? cnt[base + 0] : 0;
  int v1 = (base + 1 < NN) ? cnt[base + 1] : 0;
  int v2 = (base + 2 < NN) ? cnt[base + 2] : 0;
  int v3 = (base + 3 < NN) ? cnt[base + 3] : 0;
  const int s = v0 + v1 + v2 + v3;
  sd[t] = s;
  __syncthreads();
  for (int off = 1; off < 256; off <<= 1) {
    int x = (t >= off) ? sd[t - off] : 0;
    __syncthreads();
    sd[t] += x;
    __syncthreads();
  }
  if (t == 255) bsum[blockIdx.x] = sd[255];
  int run = sd[t] - s;
  if (base + 0 < NN) rowptr[base + 0] = run; run += v0;
  if (base + 1 < NN) rowptr[base + 1] = run; run += v1;
  if (base + 2 < NN) rowptr[base + 2] = run; run += v2;
  if (base + 3 < NN) rowptr[base + 3] = run;
}

__global__ void k_scan2(int* bsum) {
  if (threadIdx.x == 0 && blockIdx.x == 0) {
    int run = 0;
    for (int i = 0; i < NB; i++) { int t = bsum[i]; bsum[i] = run; run += t; }
  }
}

__global__ void k_scan3(const int* __restrict__ bsum, int* __restrict__ rowptr) {
  int i = blockIdx.x * 256 + threadIdx.x;
  if (i < NN) rowptr[i] = rowptr[i] + bsum[i >> 10];
  if (i == 0) rowptr[NN] = NE;
}

// ---------------- input split: A2[r] = [bf16hi(X[r]) | bf16lo(X[r])] ----------

__global__ __launch_bounds__(256) void k_split(const float* __restrict__ X,
                                               ushortT* __restrict__ A2) {
  const int gid = blockIdx.x * 256 + threadIdx.x;  // MPAD*32 total
  const int r = gid >> 5;
  const int c4 = (gid & 31) * 4;
  if (r < NN) {
    const float4 x = *reinterpret_cast<const float4*>(X + (long)r * 128 + c4);
    unsigned h0, l0, h1, l1;
    split2(x.x, x.y, h0, l0);
    split2(x.z, x.w, h1, l1);
    *reinterpret_cast<uint2*>(A2 + (long)r * 256 + c4) = make_uint2(h0, h1);
    *reinterpret_cast<uint2*>(A2 + (long)r * 256 + 128 + c4) = make_uint2(l0, l1);
  } else {
    *reinterpret_cast<uint2*>(A2 + (long)r * 256 + c4) = make_uint2(0, 0);
    *reinterpret_cast<uint2*>(A2 + (long)r * 256 + 128 + c4) = make_uint2(0, 0);
  }
}

// ---------------- W pack: B-fragment order, K=384 = [Whi; Whi; Wlo] ----------
// Bp[((ks*CG + g)*64 + lane)*8 + j] = seg(ks)[ks*32 + (lane>>4)*8 + j - off][g*16 + (lane&15)]

template <int COUT>
__global__ void k_packB(const float* __restrict__ W, ushortT* __restrict__ Bp) {
  constexpr int CG = COUT / 16;
  const int i = blockIdx.x * 256 + threadIdx.x;  // 12*CG*64*8 total
  const int j = i & 7;
  const int l = (i >> 3) & 63;
  const int rest = i >> 9;
  const int g = rest % CG;
  const int ks = rest / CG;
  const int kk = ks * 32 + (l >> 4) * 8 + j;           // 0..383
  const int k = (ks < 4) ? kk : ((ks < 8) ? kk - 128 : kk - 256);
  const int n = g * 16 + (l & 15);
  const float wv = W[k * COUT + n];
  const unsigned short h = bfr(wv);
  Bp[i] = (ks < 8) ? h : bfr(wv - bf2f(h));
}

// ---------------- MFMA GEMM: hs = bf16( (A2 as fp32-split) @ W * dinv ) -------
// No LDS, no barriers. A-frags direct from global (b128/lane = 16 full cache
// lines per instr); B-frags from pre-packed Bp (1 KB contiguous per instr,
// L1/L2-resident). 3-pass split-bf16 => fp32-accurate. Frag layouts:
// A: m=lane&15, k=quad*8+j [m120]; B: n=lane&15, k=quad*8+j [m97];
// C/D: col=lane&15, row=quad*4+reg [m89].

template <int COUT>
__global__ __launch_bounds__(256) void k_gemmM(const ushortT* __restrict__ A2,
                                               const ushortT* __restrict__ Bp,
                                               const float* __restrict__ dinv,
                                               ushortT* __restrict__ hs) {
  constexpr int CGALL = COUT / 16;              // 8 or 4
  constexpr int RG = (COUT == 128) ? 4 : 2;     // row-groups per wave
  constexpr int CG = 4;                          // col-groups per wave
  const int w = threadIdx.x >> 6;
  const int lane = threadIdx.x & 63;
  const int q = lane >> 4;
  const int c = lane & 15;
  int row0, cg0;
  if (COUT == 128) {
    row0 = blockIdx.x * 128 + (w & 1) * 64;
    cg0 = (w >> 1) * 4;                          // col0 = cg0*16
  } else {
    row0 = blockIdx.x * 128 + w * 32;
    cg0 = 0;
  }

  const ushortT* ap[RG];
#pragma unroll
  for (int rg = 0; rg < RG; rg++)
    ap[rg] = A2 + (size_t)(row0 + rg * 16 + c) * 256 + q * 8;
  const ushortT* bp0 = Bp + ((size_t)cg0 * 64 + lane) * 8;  // + ks*CGALL*512

  f4 acc[RG][CG];
#pragma unroll
  for (int i = 0; i < RG; i++)
#pragma unroll
    for (int j = 0; j < CG; j++) acc[i][j] = (f4){0.f, 0.f, 0.f, 0.f};

  sh8 af[RG], bf[CG];
#pragma unroll
  for (int rg = 0; rg < RG; rg++) af[rg] = *reinterpret_cast<const sh8*>(ap[rg]);
#pragma unroll
  for (int cg = 0; cg < CG; cg++)
    bf[cg] = *reinterpret_cast<const sh8*>(bp0 + cg * 512);

#pragma unroll
  for (int ks = 0; ks < 12; ks++) {
    sh8 an[RG], bn[CG];
    if (ks < 11) {
      const int ac = ((ks + 1) < 8) ? (ks + 1) * 32 : (ks + 1 - 8) * 32;
#pragma unroll
      for (int rg = 0; rg < RG; rg++)
        an[rg] = *reinterpret_cast<const sh8*>(ap[rg] + ac);
      const ushortT* bpk = bp0 + (size_t)(ks + 1) * CGALL * 512;
#pragma unroll
      for (int cg = 0; cg < CG; cg++)
        bn[cg] = *reinterpret_cast<const sh8*>(bpk + cg * 512);
    }
#pragma unroll
    for (int rg = 0; rg < RG; rg++)
#pragma unroll
      for (int cg = 0; cg < CG; cg++)
        acc[rg][cg] = __builtin_amdgcn_mfma_f32_16x16x32_bf16(af[rg], bf[cg],
                                                              acc[rg][cg], 0, 0, 0);
    if (ks < 11) {
#pragma unroll
      for (int rg = 0; rg < RG; rg++) af[rg] = an[rg];
#pragma unroll
      for (int cg = 0; cg < CG; cg++) bf[cg] = bn[cg];
    }
  }

  // epilogue: scale by dinv[row], round to bf16, store
#pragma unroll
  for (int rg = 0; rg < RG; rg++) {
#pragma unroll
    for (int reg = 0; reg < 4; reg++) {
      const int row = row0 + rg * 16 + q * 4 + reg;
      if (row < NN) {
        const float dv = dinv[row];
#pragma unroll
        for (int cg = 0; cg < CG; cg++) {
          hs[(size_t)row * COUT + (cg0 + cg) * 16 + c] = bfr(acc[rg][cg][reg] * dv);
        }
      }
    }
  }
}

// ---------------- aggregation (bf16 gather, fp32 accumulate) ------------------
// 128-ch output: writes hi/lo split directly into A2 layout for the next GEMM.

template <bool RELU>
__global__ __launch_bounds__(256) void k_agg128(const ushortT* __restrict__ hs,
                                                const int* __restrict__ rowptr,
                                                const int* __restrict__ col,
                                                const float* __restrict__ dinv,
                                                const float* __restrict__ bias,
                                                ushortT* __restrict__ A2) {
  const int gid = blockIdx.x * 256 + threadIdx.x;
  const int node = gid >> 6;  // one wave per node
  if (node >= NN) return;
  const int lane = threadIdx.x & 63;
  const int q = lane >> 4;          // quarter 0..3
  const int chb = (lane & 15) * 8;  // 8 channels per lane
  const int beg = rowptr[node];
  const int end = rowptr[node + 1];

  float a[8] = {};
  if (q == 0) {  // self-loop contribution
    const uint4 v = *reinterpret_cast<const uint4*>(hs + (long)node * 128 + chb);
    acc8(v, a);
  }

  int j = beg;
  if (j + 8 <= end) {
    int c0 = col[j + q];
    int c1 = col[j + 4 + q];
    while (true) {
      const uint4 v0 = *reinterpret_cast<const uint4*>(hs + (long)c0 * 128 + chb);
      const uint4 v1 = *reinterpret_cast<const uint4*>(hs + (long)c1 * 128 + chb);
      j += 8;
      const bool more = (j + 8 <= end);
      int n0, n1;
      if (more) { n0 = col[j + q]; n1 = col[j + 4 + q]; }
      acc8(v0, a);
      acc8(v1, a);
      if (!more) break;
      c0 = n0; c1 = n1;
    }
  }
  for (; j + 4 <= end; j += 4) {
    int c = col[j + q];
    const uint4 v = *reinterpret_cast<const uint4*>(hs + (long)c * 128 + chb);
    acc8(v, a);
  }
  {
    const int r = end - j;  // 0..3
    if (q < r) {
      int c = col[j + q];
      const uint4 v = *reinterpret_cast<const uint4*>(hs + (long)c * 128 + chb);
      acc8(v, a);
    }
  }

#pragma unroll
  for (int i = 0; i < 8; i++) a[i] += __shfl(a[i], lane ^ 32);
#pragma unroll
  for (int i = 0; i < 8; i++) a[i] += __shfl(a[i], lane ^ 16);

  if (q == 0) {
    const float di = dinv[node];
    const float4 b0 = *reinterpret_cast<const float4*>(bias + chb);
    const float4 b1 = *reinterpret_cast<const float4*>(bias + chb + 4);
    float o[8];
    o[0] = fmaf(a[0], di, b0.x); o[1] = fmaf(a[1], di, b0.y);
    o[2] = fmaf(a[2], di, b0.z); o[3] = fmaf(a[3], di, b0.w);
    o[4] = fmaf(a[4], di, b1.x); o[5] = fmaf(a[5], di, b1.y);
    o[6] = fmaf(a[6], di, b1.z); o[7] = fmaf(a[7], di, b1.w);
    if (RELU) {
#pragma unroll
      for (int i = 0; i < 8; i++) o[i] = fmaxf(o[i], 0.f);
    }
    uint4 H, L;
    split2(o[0], o[1], H.x, L.x);
    split2(o[2], o[3], H.y, L.y);
    split2(o[4], o[5], H.z, L.z);
    split2(o[6], o[7], H.w, L.w);
    *reinterpret_cast<uint4*>(A2 + (long)node * 256 + chb) = H;
    *reinterpret_cast<uint4*>(A2 + (long)node * 256 + 128 + chb) = L;
  }
}

__global__ __launch_bounds__(256) void k_agg64(const ushortT* __restrict__ hs,
                                               const int* __restrict__ rowptr,
                                               const int* __restrict__ col,
                                               const float* __restrict__ dinv,
                                               const float* __restrict__ bias,
                                               float* __restrict__ out) {
  const int gid = blockIdx.x * 256 + threadIdx.x;
  const int node = gid >> 6;
  if (node >= NN) return;
  const int lane = threadIdx.x & 63;
  const int o8 = lane >> 3;        // eighth 0..7
  const int chb = (lane & 7) * 8;  // 8 channels per lane
  const int beg = rowptr[node];
  const int end = rowptr[node + 1];

  float a[8] = {};
  if (o8 == 0) {  // self
    const uint4 v = *reinterpret_cast<const uint4*>(hs + (long)node * 64 + chb);
    acc8(v, a);
  }

  int j = beg;
  if (j + 16 <= end) {
    int c0 = col[j + o8];
    int c1 = col[j + 8 + o8];
    while (true) {
      const uint4 v0 = *reinterpret_cast<const uint4*>(hs + (long)c0 * 64 + chb);
      const uint4 v1 = *reinterpret_cast<const uint4*>(hs + (long)c1 * 64 + chb);
      j += 16;
      const bool more = (j + 16 <= end);
      int n0, n1;
      if (more) { n0 = col[j + o8]; n1 = col[j + 8 + o8]; }
      acc8(v0, a);
      acc8(v1, a);
      if (!more) break;
      c0 = n0; c1 = n1;
    }
  }
  for (; j + 8 <= end; j += 8) {
    int c = col[j + o8];
    const uint4 v = *reinterpret_cast<const uint4*>(hs + (long)c * 64 + chb);
    acc8(v, a);
  }
  {
    const int r = end - j;  // 0..7
    if (o8 < r) {
      int c = col[j + o8];
      const uint4 v = *reinterpret_cast<const uint4*>(hs + (long)c * 64 + chb);
      acc8(v, a);
    }
  }

#pragma unroll
  for (int i = 0; i < 8; i++) a[i] += __shfl(a[i], lane ^ 32);
#pragma unroll
  for (int i = 0; i < 8; i++) a[i] += __shfl(a[i], lane ^ 16);
#pragma unroll
  for (int i = 0; i < 8; i++) a[i] += __shfl(a[i], lane ^ 8);

  if (o8 == 0) {
    const float di = dinv[node];
    const float4 b0 = *reinterpret_cast<const float4*>(bias + chb);
    const float4 b1 = *reinterpret_cast<const float4*>(bias + chb + 4);
    float4 r0, r1;
    r0.x = fmaf(a[0], di, b0.x); r0.y = fmaf(a[1], di, b0.y);
    r0.z = fmaf(a[2], di, b0.z); r0.w = fmaf(a[3], di, b0.w);
    r1.x = fmaf(a[4], di, b1.x); r1.y = fmaf(a[5], di, b1.y);
    r1.z = fmaf(a[6], di, b1.z); r1.w = fmaf(a[7], di, b1.w);
    *reinterpret_cast<float4*>(out + (long)node * 64 + chb) = r0;
    *reinterpret_cast<float4*>(out + (long)node * 64 + chb + 4) = r1;
  }
}

// ---------------- launch ----------------

extern "C" void kernel_launch(void* const* d_in, const int* in_sizes, int n_in,
                              void* d_out, int out_size, void* d_ws, size_t ws_size,
                              hipStream_t stream) {
  const float* x  = (const float*)d_in[0];
  const int* ei   = (const int*)d_in[1];
  const float* W1 = (const float*)d_in[2];
  const float* b1 = (const float*)d_in[3];
  const float* W2 = (const float*)d_in[4];
  const float* b2 = (const float*)d_in[5];
  const float* W3 = (const float*)d_in[6];
  const float* b3 = (const float*)d_in[7];
  float* out = (float*)d_out;
  const int* srcp = ei;        // edge_index[0]
  const int* dstp = ei + NE;   // edge_index[1]

  char* wsb = (char*)d_ws;
  size_t off = 0;
  auto alloc = [&](size_t bytes) -> void* {
    void* p = wsb + off;
    off += (bytes + 255) & ~(size_t)255;
    return p;
  };
  ushortT* A2  = (ushortT*)alloc((size_t)MPAD * 256 * 2);   // [hi|lo] split input
  ushortT* hs  = (ushortT*)alloc((size_t)NN * 128 * 2);     // bf16 transform out
  int*   col    = (int*)alloc((size_t)NE * 4);
  int*   rowptr = (int*)alloc((size_t)(NN + 1) * 4);
  int*   cnt    = (int*)alloc((size_t)NN * 4);
  float* dinv   = (float*)alloc((size_t)NN * 4);
  int*   bsum   = (int*)alloc((size_t)NB * 4);
  int*   bucketCnt    = (int*)alloc((size_t)NBK * 4);
  int*   bucketBase   = (int*)alloc((size_t)(NBK + 1) * 4);
  int*   bucketCursor = (int*)alloc((size_t)NBK * 4);
  ushortT* Bp1 = (ushortT*)alloc((size_t)12 * 8 * 64 * 8 * 2);  // 96 KB
  ushortT* Bp2 = (ushortT*)alloc((size_t)12 * 8 * 64 * 8 * 2);
  ushortT* Bp3 = (ushortT*)alloc((size_t)12 * 4 * 64 * 8 * 2);  // 48 KB
  // pairArr (12.8 MB) aliases hs (25.6 MB): only live during CSR build.
  unsigned long long* pairArr = (unsigned long long*)hs;
  (void)ws_size; (void)in_sizes; (void)n_in; (void)out_size;

  const int SCB = (NE + 4095) / 4096;

  hipMemsetAsync(bucketCnt, 0, (size_t)NBK * 4, stream);
  k_hist<<<SCB, 256, 0, stream>>>(dstp, bucketCnt);
  k_scanb<<<1, 64, 0, stream>>>(bucketCnt, bucketBase, bucketCursor);
  k_scatter<<<SCB, 256, 0, stream>>>(srcp, dstp, bucketCursor, pairArr);
  k_cntdinv<<<NBK, 256, 0, stream>>>(pairArr, bucketBase, cnt, dinv);
  k_scan1<<<NB, 256, 0, stream>>>(cnt, rowptr, bsum);
  k_scan2<<<1, 64, 0, stream>>>(bsum);
  k_scan3<<<(NN + 255) / 256, 256, 0, stream>>>(bsum, rowptr);
  k_csrfill<<<NBK, 256, 0, stream>>>(pairArr, bucketBase, rowptr, col);

  // input split + weight packs (independent of CSR chain except stream order)
  k_split<<<MPAD * 32 / 256, 256, 0, stream>>>(x, A2);
  k_packB<128><<<12 * 8 * 64 * 8 / 256, 256, 0, stream>>>(W1, Bp1);
  k_packB<128><<<12 * 8 * 64 * 8 / 256, 256, 0, stream>>>(W2, Bp2);
  k_packB<64><<<12 * 4 * 64 * 8 / 256, 256, 0, stream>>>(W3, Bp3);

  const int aggGrid = (NN * 64) / 256;  // 25000
  const int gemmGrid = MPAD / 128;      // 782

  // layer 1
  k_gemmM<128><<<gemmGrid, 256, 0, stream>>>(A2, Bp1, dinv, hs);
  k_agg128<true><<<aggGrid, 256, 0, stream>>>(hs, rowptr, col, dinv, b1, A2);
  // layer 2
  k_gemmM<128><<<gemmGrid, 256, 0, stream>>>(A2, Bp2, dinv, hs);
  k_agg128<true><<<aggGrid, 256, 0, stream>>>(hs, rowptr, col, dinv, b2, A2);
  // layer 3 (128 -> 64, no relu)
  k_gemmM<64><<<gemmGrid, 256, 0, stream>>>(A2, Bp3, dinv, hs);
  k_agg64<<<aggGrid, 256, 0, stream>>>(hs, rowptr, col, dinv, b3, out);
}

// Round 8
// 435.356 us; speedup vs baseline: 1.6000x; 1.0746x over previous
//
#include <hip/hip_runtime.h>

#define NN 100000
#define NE 1600000
#define NBK 98   // buckets of 1024 nodes
#define BSH 10   // bucket = dst >> 10
#define MPAD 100096  // NN padded to 128-row tiles (782*128)

typedef unsigned short ushortT;
typedef unsigned long long ull;
using sh8 = __attribute__((ext_vector_type(8))) short;   // 8 bf16 (4 VGPR) MFMA frag
using f4  = __attribute__((ext_vector_type(4))) float;   // MFMA accumulator

// ---------------- bf16 helpers ----------------

__device__ __forceinline__ unsigned short bfr(float f) {
  unsigned u = __float_as_uint(f);
  u += 0x7FFF + ((u >> 16) & 1);
  return (unsigned short)(u >> 16);
}
__device__ __forceinline__ float bf2f(unsigned short h) {
  return __uint_as_float(((unsigned)h) << 16);
}
__device__ __forceinline__ void split2(float a, float b, unsigned& H, unsigned& L) {
  unsigned short ha = bfr(a), hb = bfr(b);
  H = (unsigned)ha | ((unsigned)hb << 16);
  L = (unsigned)bfr(a - bf2f(ha)) | ((unsigned)bfr(b - bf2f(hb)) << 16);
}
__device__ __forceinline__ void acc8(const uint4 v, float* a) {
  a[0] += __uint_as_float(v.x << 16);
  a[1] += __uint_as_float(v.x & 0xFFFF0000u);
  a[2] += __uint_as_float(v.y << 16);
  a[3] += __uint_as_float(v.y & 0xFFFF0000u);
  a[4] += __uint_as_float(v.z << 16);
  a[5] += __uint_as_float(v.z & 0xFFFF0000u);
  a[6] += __uint_as_float(v.w << 16);
  a[7] += __uint_as_float(v.w & 0xFFFF0000u);
}
__device__ __forceinline__ sh8 hi8(const float4 a, const float4 b) {
  sh8 r;
  r[0] = (short)bfr(a.x); r[1] = (short)bfr(a.y);
  r[2] = (short)bfr(a.z); r[3] = (short)bfr(a.w);
  r[4] = (short)bfr(b.x); r[5] = (short)bfr(b.y);
  r[6] = (short)bfr(b.z); r[7] = (short)bfr(b.w);
  return r;
}
__device__ __forceinline__ sh8 lo8(const float4 a, const float4 b, const sh8 h) {
  sh8 r;
  r[0] = (short)bfr(a.x - bf2f((unsigned short)h[0]));
  r[1] = (short)bfr(a.y - bf2f((unsigned short)h[1]));
  r[2] = (short)bfr(a.z - bf2f((unsigned short)h[2]));
  r[3] = (short)bfr(a.w - bf2f((unsigned short)h[3]));
  r[4] = (short)bfr(b.x - bf2f((unsigned short)h[4]));
  r[5] = (short)bfr(b.y - bf2f((unsigned short)h[5]));
  r[6] = (short)bfr(b.z - bf2f((unsigned short)h[6]));
  r[7] = (short)bfr(b.w - bf2f((unsigned short)h[7]));
  return r;
}

// ---------------- bucketed CSR build ----------------

__global__ void k_hist(const int* __restrict__ dst, int* __restrict__ bucketCnt) {
  __shared__ int lc[NBK];
  const int t = threadIdx.x;
  for (int i = t; i < NBK; i += 256) lc[i] = 0;
  __syncthreads();
  const int base = blockIdx.x * 4096;
#pragma unroll
  for (int q = 0; q < 16; q++) {
    int e = base + t + 256 * q;
    if (e < NE) atomicAdd(&lc[dst[e] >> BSH], 1);
  }
  __syncthreads();
  for (int i = t; i < NBK; i += 256)
    if (lc[i]) atomicAdd(&bucketCnt[i], lc[i]);
}

__global__ void k_scanb(const int* __restrict__ bucketCnt, int* __restrict__ bucketBase,
                        int* __restrict__ bucketCursor) {
  if (threadIdx.x == 0) {
    int run = 0;
    for (int i = 0; i < NBK; i++) {
      bucketBase[i] = run;
      bucketCursor[i] = run;
      run += bucketCnt[i];
    }
    bucketBase[NBK] = run;  // == NE
  }
}

__global__ __launch_bounds__(256) void k_scatter(const int* __restrict__ src,
                                                 const int* __restrict__ dst,
                                                 int* __restrict__ bucketCursor,
                                                 ull* __restrict__ pairArr) {
  __shared__ int lcnt[NBK];
  __shared__ int lbase[NBK];
  __shared__ int lrank[NBK];
  __shared__ int bbase[NBK];
  __shared__ ull sorted[4096];
  __shared__ int target[4096];
  const int t = threadIdx.x;
  for (int i = t; i < NBK; i += 256) { lcnt[i] = 0; lrank[i] = 0; }
  __syncthreads();
  const int base = blockIdx.x * 4096;
  int rs[16], rd[16];
#pragma unroll
  for (int q = 0; q < 16; q++) {
    int e = base + t + 256 * q;
    rs[q] = (e < NE) ? src[e] : -1;
    rd[q] = (e < NE) ? dst[e] : -1;
    if (rd[q] >= 0) atomicAdd(&lcnt[rd[q] >> BSH], 1);
  }
  __syncthreads();
  if (t == 0) {
    int run = 0;
    for (int i = 0; i < NBK; i++) { lbase[i] = run; run += lcnt[i]; }
  }
  __syncthreads();
  if (t < NBK && lcnt[t] > 0) bbase[t] = atomicAdd(&bucketCursor[t], lcnt[t]);
  __syncthreads();
#pragma unroll
  for (int q = 0; q < 16; q++) {
    if (rd[q] >= 0) {
      int b = rd[q] >> BSH;
      int r = atomicAdd(&lrank[b], 1);
      int slot = lbase[b] + r;
      sorted[slot] = ((ull)(unsigned)rs[q] << 32) | (unsigned)rd[q];
      target[slot] = bbase[b] + r;
    }
  }
  __syncthreads();
  const int n = min(4096, NE - base);
  for (int s = t; s < n; s += 256) pairArr[target[s]] = sorted[s];
}

// One block per bucket: counts -> dinv + rowptr (bucketBase + local scan),
// then CSR col fill via LDS cursors. Replaces cntdinv/scan1/scan2/scan3/csrfill.
__global__ __launch_bounds__(256) void k_buildcsr(const ull* __restrict__ pairArr,
                                                  const int* __restrict__ bucketBase,
                                                  float* __restrict__ dinv,
                                                  int* __restrict__ rowptr,
                                                  int* __restrict__ col) {
  __shared__ int lc[1024];
  __shared__ int sd[256];
  const int t = threadIdx.x;
  const int b = blockIdx.x;
  const int n0 = b << BSH;
  for (int i = t; i < 1024; i += 256) lc[i] = 0;
  __syncthreads();
  const int ebeg = bucketBase[b], eend = bucketBase[b + 1];
  for (int i = ebeg + t; i < eend; i += 256)
    atomicAdd(&lc[(int)(unsigned)(pairArr[i] & 0xffffffffULL) - n0], 1);
  __syncthreads();
  const int v0 = lc[t * 4], v1 = lc[t * 4 + 1], v2 = lc[t * 4 + 2], v3 = lc[t * 4 + 3];
  const int s = v0 + v1 + v2 + v3;
  sd[t] = s;
  __syncthreads();
  for (int off = 1; off < 256; off <<= 1) {
    int x = (t >= off) ? sd[t - off] : 0;
    __syncthreads();
    sd[t] += x;
    __syncthreads();
  }
  const int run = sd[t] - s;  // exclusive within bucket
  const int c0 = run, c1 = run + v0, c2 = c1 + v1, c3 = c2 + v2;
  lc[t * 4] = c0; lc[t * 4 + 1] = c1; lc[t * 4 + 2] = c2; lc[t * 4 + 3] = c3;
  const int cnts[4] = {v0, v1, v2, v3};
  const int curs[4] = {c0, c1, c2, c3};
#pragma unroll
  for (int i = 0; i < 4; i++) {
    int node = n0 + t * 4 + i;
    if (node < NN) {
      rowptr[node] = ebeg + curs[i];
      dinv[node] = rsqrtf(1.0f + (float)cnts[i]);  // self-loop => deg >= 1
    }
  }
  if (b == 0 && t == 0) rowptr[NN] = NE;
  __syncthreads();
  for (int i = ebeg + t; i < eend; i += 256) {
    ull p = pairArr[i];
    int d = (int)(unsigned)(p & 0xffffffffULL);
    int srcv = (int)(unsigned)(p >> 32);
    int pos = atomicAdd(&lc[d - n0], 1);
    col[ebeg + pos] = srcv;
  }
}

// ---------------- W pack: 8 segments = [Whi kr0..3 | Wlo kr0..3] -------------
// Bp[((ks*CG + g)*64 + lane)*8 + j] ; k = (ks&3)*32 + (lane>>4)*8 + j,
// n = g*16 + (lane&15); hi for ks<4, lo for ks>=4.

template <int COUT>
__device__ __forceinline__ void packone(const float* __restrict__ W,
                                        ushortT* __restrict__ Bp, int i) {
  const int j = i & 7;
  const int l = (i >> 3) & 63;
  const int rest = i >> 9;
  const int g = rest % (COUT / 16);
  const int ks = rest / (COUT / 16);
  const int k = (ks & 3) * 32 + (l >> 4) * 8 + j;
  const int n = g * 16 + (l & 15);
  const float v = W[k * COUT + n];
  const unsigned short h = bfr(v);
  Bp[i] = (ks < 4) ? h : bfr(v - bf2f(h));
}

__global__ void k_packAll(const float* __restrict__ W1, const float* __restrict__ W2,
                          const float* __restrict__ W3, ushortT* __restrict__ Bp1,
                          ushortT* __restrict__ Bp2, ushortT* __restrict__ Bp3) {
  const int i = blockIdx.x * 256 + threadIdx.x;  // 0..81919
  if (i < 32768) packone<128>(W1, Bp1, i);
  else if (i < 65536) packone<128>(W2, Bp2, i - 32768);
  else packone<64>(W3, Bp3, i - 65536);
}

// ---------------- MFMA GEMM: hs = bf16( X @ W * dinv ), split-bf16 3-pass ----
// Residue-major K-loop: per 32-wide chunk load A once (hi,lo), B (bHi,bLo),
// 3 MFMAs per (rg,cg): hi*bHi + lo*bHi + hi*bLo  => fp32-accurate.
// FUSED: A read as fp32 X, split in-register (layer 1 — kills k_split pass).
// Frag layouts: A m=lane&15,k=quad*8+j [m120]; B n=lane&15 [m97];
// C/D col=lane&15,row=quad*4+reg [m89].

template <int COUT, bool FUSED>
__global__ __launch_bounds__(256) void k_gemmM(const ushortT* __restrict__ A2,
                                               const float* __restrict__ X,
                                               const ushortT* __restrict__ Bp,
                                               const float* __restrict__ dinv,
                                               ushortT* __restrict__ hs) {
  constexpr int CGALL = COUT / 16;              // 8 or 4
  constexpr int RG = (COUT == 128) ? 4 : 2;     // row-groups per wave
  constexpr int CG = 4;                          // col-groups per wave
  const int w = threadIdx.x >> 6;
  const int lane = threadIdx.x & 63;
  const int q = lane >> 4;
  const int c = lane & 15;
  int row0, cg0;
  if (COUT == 128) {
    row0 = blockIdx.x * 128 + (w & 1) * 64;
    cg0 = (w >> 1) * 4;
  } else {
    row0 = blockIdx.x * 128 + w * 32;
    cg0 = 0;
  }

  const ushortT* ap[RG];
  const float* xp[RG];
#pragma unroll
  for (int rg = 0; rg < RG; rg++) {
    const int row = row0 + rg * 16 + c;
    if (FUSED) xp[rg] = X + (size_t)min(row, NN - 1) * 128 + q * 8;
    else ap[rg] = A2 + (size_t)row * 256 + q * 8;
  }
  const ushortT* bp0 = Bp + (size_t)lane * 8;

  f4 acc[RG][CG];
#pragma unroll
  for (int i = 0; i < RG; i++)
#pragma unroll
    for (int j = 0; j < CG; j++) acc[i][j] = (f4){0.f, 0.f, 0.f, 0.f};

  sh8 ah[RG], al[RG], bh[CG], bl[CG];
  sh8 nah[RG], nal[RG], nbh[CG], nbl[CG];

  auto loadA = [&](int kr, sh8 (&h)[RG], sh8 (&l)[RG]) {
#pragma unroll
    for (int rg = 0; rg < RG; rg++) {
      if (FUSED) {
        const float4 x0 = *reinterpret_cast<const float4*>(xp[rg] + kr * 32);
        const float4 x1 = *reinterpret_cast<const float4*>(xp[rg] + kr * 32 + 4);
        h[rg] = hi8(x0, x1);
        l[rg] = lo8(x0, x1, h[rg]);
      } else {
        h[rg] = *reinterpret_cast<const sh8*>(ap[rg] + kr * 32);
        l[rg] = *reinterpret_cast<const sh8*>(ap[rg] + 128 + kr * 32);
      }
    }
  };
  auto loadB = [&](int kr, sh8 (&h)[CG], sh8 (&l)[CG]) {
#pragma unroll
    for (int cg = 0; cg < CG; cg++) {
      h[cg] = *reinterpret_cast<const sh8*>(bp0 + (size_t)(kr * CGALL + cg0 + cg) * 512);
      l[cg] = *reinterpret_cast<const sh8*>(bp0 + (size_t)((4 + kr) * CGALL + cg0 + cg) * 512);
    }
  };

  loadA(0, ah, al);
  loadB(0, bh, bl);
#pragma unroll
  for (int kr = 0; kr < 4; kr++) {
    if (kr < 3) {
      loadA(kr + 1, nah, nal);
      loadB(kr + 1, nbh, nbl);
    }
#pragma unroll
    for (int rg = 0; rg < RG; rg++)
#pragma unroll
      for (int cg = 0; cg < CG; cg++)
        acc[rg][cg] = __builtin_amdgcn_mfma_f32_16x16x32_bf16(ah[rg], bh[cg],
                                                              acc[rg][cg], 0, 0, 0);
#pragma unroll
    for (int rg = 0; rg < RG; rg++)
#pragma unroll
      for (int cg = 0; cg < CG; cg++)
        acc[rg][cg] = __builtin_amdgcn_mfma_f32_16x16x32_bf16(al[rg], bh[cg],
                                                              acc[rg][cg], 0, 0, 0);
#pragma unroll
    for (int rg = 0; rg < RG; rg++)
#pragma unroll
      for (int cg = 0; cg < CG; cg++)
        acc[rg][cg] = __builtin_amdgcn_mfma_f32_16x16x32_bf16(ah[rg], bl[cg],
                                                              acc[rg][cg], 0, 0, 0);
    if (kr < 3) {
#pragma unroll
      for (int rg = 0; rg < RG; rg++) { ah[rg] = nah[rg]; al[rg] = nal[rg]; }
#pragma unroll
      for (int cg = 0; cg < CG; cg++) { bh[cg] = nbh[cg]; bl[cg] = nbl[cg]; }
    }
  }

  // epilogue: scale by dinv[row], round to bf16, store
#pragma unroll
  for (int rg = 0; rg < RG; rg++) {
#pragma unroll
    for (int reg = 0; reg < 4; reg++) {
      const int row = row0 + rg * 16 + q * 4 + reg;
      if (row < NN) {
        const float dv = dinv[row];
#pragma unroll
        for (int cg = 0; cg < CG; cg++) {
          hs[(size_t)row * COUT + (cg0 + cg) * 16 + c] = bfr(acc[rg][cg][reg] * dv);
        }
      }
    }
  }
}

// ---------------- aggregation (bf16 gather, fp32 accumulate) ------------------

template <bool RELU>
__global__ __launch_bounds__(256) void k_agg128(const ushortT* __restrict__ hs,
                                                const int* __restrict__ rowptr,
                                                const int* __restrict__ col,
                                                const float* __restrict__ dinv,
                                                const float* __restrict__ bias,
                                                ushortT* __restrict__ A2) {
  const int gid = blockIdx.x * 256 + threadIdx.x;
  const int node = gid >> 6;  // one wave per node
  if (node >= NN) return;
  const int lane = threadIdx.x & 63;
  const int q = lane >> 4;          // quarter 0..3
  const int chb = (lane & 15) * 8;  // 8 channels per lane
  const int beg = rowptr[node];
  const int end = rowptr[node + 1];

  float a[8] = {};
  if (q == 0) {  // self-loop contribution
    const uint4 v = *reinterpret_cast<const uint4*>(hs + (long)node * 128 + chb);
    acc8(v, a);
  }

  int j = beg;
  if (j + 8 <= end) {
    int c0 = col[j + q];
    int c1 = col[j + 4 + q];
    while (true) {
      const uint4 v0 = *reinterpret_cast<const uint4*>(hs + (long)c0 * 128 + chb);
      const uint4 v1 = *reinterpret_cast<const uint4*>(hs + (long)c1 * 128 + chb);
      j += 8;
      const bool more = (j + 8 <= end);
      int n0, n1;
      if (more) { n0 = col[j + q]; n1 = col[j + 4 + q]; }
      acc8(v0, a);
      acc8(v1, a);
      if (!more) break;
      c0 = n0; c1 = n1;
    }
  }
  for (; j + 4 <= end; j += 4) {
    int c = col[j + q];
    const uint4 v = *reinterpret_cast<const uint4*>(hs + (long)c * 128 + chb);
    acc8(v, a);
  }
  {
    const int r = end - j;  // 0..3
    if (q < r) {
      int c = col[j + q];
      const uint4 v = *reinterpret_cast<const uint4*>(hs + (long)c * 128 + chb);
      acc8(v, a);
    }
  }

#pragma unroll
  for (int i = 0; i < 8; i++) a[i] += __shfl(a[i], lane ^ 32);
#pragma unroll
  for (int i = 0; i < 8; i++) a[i] += __shfl(a[i], lane ^ 16);

  if (q == 0) {
    const float di = dinv[node];
    const float4 b0 = *reinterpret_cast<const float4*>(bias + chb);
    const float4 b1 = *reinterpret_cast<const float4*>(bias + chb + 4);
    float o[8];
    o[0] = fmaf(a[0], di, b0.x); o[1] = fmaf(a[1], di, b0.y);
    o[2] = fmaf(a[2], di, b0.z); o[3] = fmaf(a[3], di, b0.w);
    o[4] = fmaf(a[4], di, b1.x); o[5] = fmaf(a[5], di, b1.y);
    o[6] = fmaf(a[6], di, b1.z); o[7] = fmaf(a[7], di, b1.w);
    if (RELU) {
#pragma unroll
      for (int i = 0; i < 8; i++) o[i] = fmaxf(o[i], 0.f);
    }
    uint4 H, L;
    split2(o[0], o[1], H.x, L.x);
    split2(o[2], o[3], H.y, L.y);
    split2(o[4], o[5], H.z, L.z);
    split2(o[6], o[7], H.w, L.w);
    *reinterpret_cast<uint4*>(A2 + (long)node * 256 + chb) = H;
    *reinterpret_cast<uint4*>(A2 + (long)node * 256 + 128 + chb) = L;
  }
}

__global__ __launch_bounds__(256) void k_agg64(const ushortT* __restrict__ hs,
                                               const int* __restrict__ rowptr,
                                               const int* __restrict__ col,
                                               const float* __restrict__ dinv,
                                               const float* __restrict__ bias,
                                               float* __restrict__ out) {
  const int gid = blockIdx.x * 256 + threadIdx.x;
  const int node = gid >> 6;
  if (node >= NN) return;
  const int lane = threadIdx.x & 63;
  const int o8 = lane >> 3;        // eighth 0..7
  const int chb = (lane & 7) * 8;  // 8 channels per lane
  const int beg = rowptr[node];
  const int end = rowptr[node + 1];

  float a[8] = {};
  if (o8 == 0) {  // self
    const uint4 v = *reinterpret_cast<const uint4*>(hs + (long)node * 64 + chb);
    acc8(v, a);
  }

  int j = beg;
  if (j + 16 <= end) {
    int c0 = col[j + o8];
    int c1 = col[j + 8 + o8];
    while (true) {
      const uint4 v0 = *reinterpret_cast<const uint4*>(hs + (long)c0 * 64 + chb);
      const uint4 v1 = *reinterpret_cast<const uint4*>(hs + (long)c1 * 64 + chb);
      j += 16;
      const bool more = (j + 16 <= end);
      int n0, n1;
      if (more) { n0 = col[j + o8]; n1 = col[j + 8 + o8]; }
      acc8(v0, a);
      acc8(v1, a);
      if (!more) break;
      c0 = n0; c1 = n1;
    }
  }
  for (; j + 8 <= end; j += 8) {
    int c = col[j + o8];
    const uint4 v = *reinterpret_cast<const uint4*>(hs + (long)c * 64 + chb);
    acc8(v, a);
  }
  {
    const int r = end - j;  // 0..7
    if (o8 < r) {
      int c = col[j + o8];
      const uint4 v = *reinterpret_cast<const uint4*>(hs + (long)c * 64 + chb);
      acc8(v, a);
    }
  }

#pragma unroll
  for (int i = 0; i < 8; i++) a[i] += __shfl(a[i], lane ^ 32);
#pragma unroll
  for (int i = 0; i < 8; i++) a[i] += __shfl(a[i], lane ^ 16);
#pragma unroll
  for (int i = 0; i < 8; i++) a[i] += __shfl(a[i], lane ^ 8);

  if (o8 == 0) {
    const float di = dinv[node];
    const float4 b0 = *reinterpret_cast<const float4*>(bias + chb);
    const float4 b1 = *reinterpret_cast<const float4*>(bias + chb + 4);
    float4 r0, r1;
    r0.x = fmaf(a[0], di, b0.x); r0.y = fmaf(a[1], di, b0.y);
    r0.z = fmaf(a[2], di, b0.z); r0.w = fmaf(a[3], di, b0.w);
    r1.x = fmaf(a[4], di, b1.x); r1.y = fmaf(a[5], di, b1.y);
    r1.z = fmaf(a[6], di, b1.z); r1.w = fmaf(a[7], di, b1.w);
    *reinterpret_cast<float4*>(out + (long)node * 64 + chb) = r0;
    *reinterpret_cast<float4*>(out + (long)node * 64 + chb + 4) = r1;
  }
}

// ---------------- launch ----------------

extern "C" void kernel_launch(void* const* d_in, const int* in_sizes, int n_in,
                              void* d_out, int out_size, void* d_ws, size_t ws_size,
                              hipStream_t stream) {
  const float* x  = (const float*)d_in[0];
  const int* ei   = (const int*)d_in[1];
  const float* W1 = (const float*)d_in[2];
  const float* b1 = (const float*)d_in[3];
  const float* W2 = (const float*)d_in[4];
  const float* b2 = (const float*)d_in[5];
  const float* W3 = (const float*)d_in[6];
  const float* b3 = (const float*)d_in[7];
  float* out = (float*)d_out;
  const int* srcp = ei;        // edge_index[0]
  const int* dstp = ei + NE;   // edge_index[1]

  char* wsb = (char*)d_ws;
  size_t off = 0;
  auto alloc = [&](size_t bytes) -> void* {
    void* p = wsb + off;
    off += (bytes + 255) & ~(size_t)255;
    return p;
  };
  ushortT* A2  = (ushortT*)alloc((size_t)MPAD * 256 * 2);   // [hi|lo] activations
  ushortT* hs  = (ushortT*)alloc((size_t)NN * 128 * 2);     // bf16 transform out
  int*   col    = (int*)alloc((size_t)NE * 4);
  int*   rowptr = (int*)alloc((size_t)(NN + 1) * 4);
  float* dinv   = (float*)alloc((size_t)NN * 4);
  int*   bucketCnt    = (int*)alloc((size_t)NBK * 4);
  int*   bucketBase   = (int*)alloc((size_t)(NBK + 1) * 4);
  int*   bucketCursor = (int*)alloc((size_t)NBK * 4);
  ushortT* Bp1 = (ushortT*)alloc((size_t)32768 * 2);  // 8 seg x 8 cg x 512
  ushortT* Bp2 = (ushortT*)alloc((size_t)32768 * 2);
  ushortT* Bp3 = (ushortT*)alloc((size_t)16384 * 2);  // 8 seg x 4 cg x 512
  // pairArr (12.8 MB) aliases hs (25.6 MB): only live during CSR build.
  ull* pairArr = (ull*)hs;
  (void)ws_size; (void)in_sizes; (void)n_in; (void)out_size;

  const int SCB = (NE + 4095) / 4096;  // 391

  hipMemsetAsync(bucketCnt, 0, (size_t)NBK * 4, stream);
  k_hist<<<SCB, 256, 0, stream>>>(dstp, bucketCnt);
  k_scanb<<<1, 64, 0, stream>>>(bucketCnt, bucketBase, bucketCursor);
  k_scatter<<<SCB, 256, 0, stream>>>(srcp, dstp, bucketCursor, pairArr);
  k_buildcsr<<<NBK, 256, 0, stream>>>(pairArr, bucketBase, dinv, rowptr, col);
  k_packAll<<<320, 256, 0, stream>>>(W1, W2, W3, Bp1, Bp2, Bp3);

  const int aggGrid = (NN * 64) / 256;  // 25000
  const int gemmGrid = MPAD / 128;      // 782

  // layer 1 (fused fp32 split — reads X directly)
  k_gemmM<128, true><<<gemmGrid, 256, 0, stream>>>(nullptr, x, Bp1, dinv, hs);
  k_agg128<true><<<aggGrid, 256, 0, stream>>>(hs, rowptr, col, dinv, b1, A2);
  // layer 2
  k_gemmM<128, false><<<gemmGrid, 256, 0, stream>>>(A2, nullptr, Bp2, dinv, hs);
  k_agg128<true><<<aggGrid, 256, 0, stream>>>(hs, rowptr, col, dinv, b2, A2);
  // layer 3 (128 -> 64, no relu)
  k_gemmM<64, false><<<gemmGrid, 256, 0, stream>>>(A2, nullptr, Bp3, dinv, hs);
  k_agg64<<<aggGrid, 256, 0, stream>>>(hs, rowptr, col, dinv, b3, out);
}

// Round 9
// 411.377 us; speedup vs baseline: 1.6933x; 1.0583x over previous
//
#include <hip/hip_runtime.h>

#define NN 100000
#define NE 1600000
#define NBK 98   // buckets of 1024 nodes
#define BSH 10   // bucket = dst >> 10
#define MPAD 100096  // NN padded to 128-row tiles (782*128)
#define SCB 391      // ceil(NE/4096) scatter blocks
#define CAP 20480    // padded slots per bucket (expected max ~16.8K)

typedef unsigned short ushortT;
typedef unsigned long long ull;
using sh8 = __attribute__((ext_vector_type(8))) short;   // 8 bf16 (4 VGPR) MFMA frag
using f4  = __attribute__((ext_vector_type(4))) float;   // MFMA accumulator

// ---------------- bf16 helpers ----------------

__device__ __forceinline__ unsigned short bfr(float f) {
  unsigned u = __float_as_uint(f);
  u += 0x7FFF + ((u >> 16) & 1);
  return (unsigned short)(u >> 16);
}
__device__ __forceinline__ float bf2f(unsigned short h) {
  return __uint_as_float(((unsigned)h) << 16);
}
__device__ __forceinline__ void split2(float a, float b, unsigned& H, unsigned& L) {
  unsigned short ha = bfr(a), hb = bfr(b);
  H = (unsigned)ha | ((unsigned)hb << 16);
  L = (unsigned)bfr(a - bf2f(ha)) | ((unsigned)bfr(b - bf2f(hb)) << 16);
}
__device__ __forceinline__ void acc8(const uint4 v, float* a) {
  a[0] += __uint_as_float(v.x << 16);
  a[1] += __uint_as_float(v.x & 0xFFFF0000u);
  a[2] += __uint_as_float(v.y << 16);
  a[3] += __uint_as_float(v.y & 0xFFFF0000u);
  a[4] += __uint_as_float(v.z << 16);
  a[5] += __uint_as_float(v.z & 0xFFFF0000u);
  a[6] += __uint_as_float(v.w << 16);
  a[7] += __uint_as_float(v.w & 0xFFFF0000u);
}
__device__ __forceinline__ sh8 hi8(const float4 a, const float4 b) {
  sh8 r;
  r[0] = (short)bfr(a.x); r[1] = (short)bfr(a.y);
  r[2] = (short)bfr(a.z); r[3] = (short)bfr(a.w);
  r[4] = (short)bfr(b.x); r[5] = (short)bfr(b.y);
  r[6] = (short)bfr(b.z); r[7] = (short)bfr(b.w);
  return r;
}
__device__ __forceinline__ sh8 lo8(const float4 a, const float4 b, const sh8 h) {
  sh8 r;
  r[0] = (short)bfr(a.x - bf2f((unsigned short)h[0]));
  r[1] = (short)bfr(a.y - bf2f((unsigned short)h[1]));
  r[2] = (short)bfr(a.z - bf2f((unsigned short)h[2]));
  r[3] = (short)bfr(a.w - bf2f((unsigned short)h[3]));
  r[4] = (short)bfr(b.x - bf2f((unsigned short)h[4]));
  r[5] = (short)bfr(b.y - bf2f((unsigned short)h[5]));
  r[6] = (short)bfr(b.z - bf2f((unsigned short)h[6]));
  r[7] = (short)bfr(b.w - bf2f((unsigned short)h[7]));
  return r;
}

// ---------------- W pack helper ----------------
// Bp[((ks*CG + g)*64 + lane)*8 + j]; k=(ks&3)*32+(lane>>4)*8+j, n=g*16+(lane&15)
// hi for ks<4, lo residue for ks>=4.

template <int COUT>
__device__ __forceinline__ void packone(const float* __restrict__ W,
                                        ushortT* __restrict__ Bp, int i) {
  const int j = i & 7;
  const int l = (i >> 3) & 63;
  const int rest = i >> 9;
  const int g = rest % (COUT / 16);
  const int ks = rest / (COUT / 16);
  const int k = (ks & 3) * 32 + (l >> 4) * 8 + j;
  const int n = g * 16 + (l & 15);
  const float v = W[k * COUT + n];
  const unsigned short h = bfr(v);
  Bp[i] = (ks < 4) ? h : bfr(v - bf2f(h));
}

// ---------------- fused scatter (padded buckets) + weight pack ---------------
// Blocks [0,SCB): LDS-sort 4096 edges into 1024-node buckets, reserve runs in
// the bucket's padded window via one global atomic per (block,bucket), flush
// coalesced. Blocks [SCB, SCB+320): pack W1/W2/W3 into B-fragment order.

__global__ __launch_bounds__(256) void k_scatterpack(
    const int* __restrict__ src, const int* __restrict__ dst,
    int* __restrict__ cursor, ull* __restrict__ pairArr,
    const float* __restrict__ W1, const float* __restrict__ W2,
    const float* __restrict__ W3, ushortT* __restrict__ Bp1,
    ushortT* __restrict__ Bp2, ushortT* __restrict__ Bp3) {
  if (blockIdx.x >= SCB) {
    const int i = (blockIdx.x - SCB) * 256 + threadIdx.x;  // 0..81919
    if (i < 32768) packone<128>(W1, Bp1, i);
    else if (i < 65536) packone<128>(W2, Bp2, i - 32768);
    else packone<64>(W3, Bp3, i - 65536);
    return;
  }
  __shared__ int lcnt[NBK];
  __shared__ int lbase[NBK];
  __shared__ int lrank[NBK];
  __shared__ int bbase[NBK];
  __shared__ ull sorted[4096];
  __shared__ int target[4096];
  const int t = threadIdx.x;
  for (int i = t; i < NBK; i += 256) { lcnt[i] = 0; lrank[i] = 0; }
  __syncthreads();
  const int base = blockIdx.x * 4096;
  int rs[16], rd[16];
#pragma unroll
  for (int q = 0; q < 16; q++) {
    int e = base + t + 256 * q;
    rs[q] = (e < NE) ? src[e] : -1;
    rd[q] = (e < NE) ? dst[e] : -1;
    if (rd[q] >= 0) atomicAdd(&lcnt[rd[q] >> BSH], 1);
  }
  __syncthreads();
  if (t == 0) {
    int run = 0;
    for (int i = 0; i < NBK; i++) { lbase[i] = run; run += lcnt[i]; }
  }
  __syncthreads();
  if (t < NBK && lcnt[t] > 0) bbase[t] = atomicAdd(&cursor[t], lcnt[t]);
  __syncthreads();
#pragma unroll
  for (int q = 0; q < 16; q++) {
    if (rd[q] >= 0) {
      int b = rd[q] >> BSH;
      int r = atomicAdd(&lrank[b], 1);
      int slot = lbase[b] + r;
      sorted[slot] = ((ull)(unsigned)rs[q] << 32) | (unsigned)rd[q];
      target[slot] = b * CAP + bbase[b] + r;  // padded-bucket placement
    }
  }
  __syncthreads();
  const int n = min(4096, NE - base);
  for (int s = t; s < n; s += 256) pairArr[target[s]] = sorted[s];
}

// ---------------- CSR build: one block per bucket ----------------------------
// cursor[b] == bucket edge count after scatter. Global edge base = in-block
// 98-prefix. Counts -> dinv + rowptr, then col fill via LDS cursors.

__global__ __launch_bounds__(256) void k_buildcsr(const ull* __restrict__ pairArr,
                                                  const int* __restrict__ cnt,
                                                  float* __restrict__ dinv,
                                                  int* __restrict__ rowptr,
                                                  int* __restrict__ col) {
  __shared__ int lc[1024];
  __shared__ int sd[256];
  __shared__ int bc[NBK];
  __shared__ int ebegS;
  const int t = threadIdx.x;
  const int b = blockIdx.x;
  const int n0 = b << BSH;
  if (t < NBK) bc[t] = cnt[t];
  for (int i = t; i < 1024; i += 256) lc[i] = 0;
  __syncthreads();
  if (t == 0) {
    int run = 0;
    for (int i = 0; i < b; i++) run += bc[i];
    ebegS = run;
  }
  __syncthreads();
  const int ebeg = ebegS;
  const int myCnt = bc[b];
  const ull* pb = pairArr + (size_t)b * CAP;
  for (int i = t; i < myCnt; i += 256)
    atomicAdd(&lc[(int)(unsigned)(pb[i] & 0xffffffffULL) - n0], 1);
  __syncthreads();
  const int v0 = lc[t * 4], v1 = lc[t * 4 + 1], v2 = lc[t * 4 + 2], v3 = lc[t * 4 + 3];
  const int s = v0 + v1 + v2 + v3;
  sd[t] = s;
  __syncthreads();
  for (int off = 1; off < 256; off <<= 1) {
    int x = (t >= off) ? sd[t - off] : 0;
    __syncthreads();
    sd[t] += x;
    __syncthreads();
  }
  const int run = sd[t] - s;  // exclusive within bucket
  const int c0 = run, c1 = run + v0, c2 = c1 + v1, c3 = c2 + v2;
  lc[t * 4] = c0; lc[t * 4 + 1] = c1; lc[t * 4 + 2] = c2; lc[t * 4 + 3] = c3;
  const int cnts[4] = {v0, v1, v2, v3};
  const int curs[4] = {c0, c1, c2, c3};
#pragma unroll
  for (int i = 0; i < 4; i++) {
    int node = n0 + t * 4 + i;
    if (node < NN) {
      rowptr[node] = ebeg + curs[i];
      dinv[node] = rsqrtf(1.0f + (float)cnts[i]);  // self-loop => deg >= 1
    }
  }
  if (b == 0 && t == 0) rowptr[NN] = NE;
  __syncthreads();
  for (int i = t; i < myCnt; i += 256) {
    ull p = pb[i];
    int d = (int)(unsigned)(p & 0xffffffffULL);
    int srcv = (int)(unsigned)(p >> 32);
    int pos = atomicAdd(&lc[d - n0], 1);
    col[ebeg + pos] = srcv;
  }
}

// ---------------- MFMA GEMM: hs = bf16( X @ W * dinv ), split-bf16 3-pass ----
// Residue-major K-loop: per 32-wide chunk load A once (hi,lo), B (bHi,bLo),
// 3 MFMAs per (rg,cg): hi*bHi + lo*bHi + hi*bLo => fp32-accurate.
// FUSED: layer 1 reads fp32 X directly, splits in-register.
// Frag layouts: A m=lane&15,k=quad*8+j [m120]; B n=lane&15 [m97];
// C/D col=lane&15,row=quad*4+reg [m89].

template <int COUT, bool FUSED>
__global__ __launch_bounds__(256) void k_gemmM(const ushortT* __restrict__ A2,
                                               const float* __restrict__ X,
                                               const ushortT* __restrict__ Bp,
                                               const float* __restrict__ dinv,
                                               ushortT* __restrict__ hs) {
  constexpr int CGALL = COUT / 16;              // 8 or 4
  constexpr int RG = (COUT == 128) ? 4 : 2;     // row-groups per wave
  constexpr int CG = 4;                          // col-groups per wave
  const int w = threadIdx.x >> 6;
  const int lane = threadIdx.x & 63;
  const int q = lane >> 4;
  const int c = lane & 15;
  int row0, cg0;
  if (COUT == 128) {
    row0 = blockIdx.x * 128 + (w & 1) * 64;
    cg0 = (w >> 1) * 4;
  } else {
    row0 = blockIdx.x * 128 + w * 32;
    cg0 = 0;
  }

  const ushortT* ap[RG];
  const float* xp[RG];
#pragma unroll
  for (int rg = 0; rg < RG; rg++) {
    const int row = row0 + rg * 16 + c;
    if (FUSED) xp[rg] = X + (size_t)min(row, NN - 1) * 128 + q * 8;
    else ap[rg] = A2 + (size_t)row * 256 + q * 8;
  }
  const ushortT* bp0 = Bp + (size_t)lane * 8;

  f4 acc[RG][CG];
#pragma unroll
  for (int i = 0; i < RG; i++)
#pragma unroll
    for (int j = 0; j < CG; j++) acc[i][j] = (f4){0.f, 0.f, 0.f, 0.f};

  sh8 ah[RG], al[RG], bh[CG], bl[CG];
  sh8 nah[RG], nal[RG], nbh[CG], nbl[CG];

  auto loadA = [&](int kr, sh8 (&h)[RG], sh8 (&l)[RG]) {
#pragma unroll
    for (int rg = 0; rg < RG; rg++) {
      if (FUSED) {
        const float4 x0 = *reinterpret_cast<const float4*>(xp[rg] + kr * 32);
        const float4 x1 = *reinterpret_cast<const float4*>(xp[rg] + kr * 32 + 4);
        h[rg] = hi8(x0, x1);
        l[rg] = lo8(x0, x1, h[rg]);
      } else {
        h[rg] = *reinterpret_cast<const sh8*>(ap[rg] + kr * 32);
        l[rg] = *reinterpret_cast<const sh8*>(ap[rg] + 128 + kr * 32);
      }
    }
  };
  auto loadB = [&](int kr, sh8 (&h)[CG], sh8 (&l)[CG]) {
#pragma unroll
    for (int cg = 0; cg < CG; cg++) {
      h[cg] = *reinterpret_cast<const sh8*>(bp0 + (size_t)(kr * CGALL + cg0 + cg) * 512);
      l[cg] = *reinterpret_cast<const sh8*>(bp0 + (size_t)((4 + kr) * CGALL + cg0 + cg) * 512);
    }
  };

  loadA(0, ah, al);
  loadB(0, bh, bl);
#pragma unroll
  for (int kr = 0; kr < 4; kr++) {
    if (kr < 3) {
      loadA(kr + 1, nah, nal);
      loadB(kr + 1, nbh, nbl);
    }
#pragma unroll
    for (int rg = 0; rg < RG; rg++)
#pragma unroll
      for (int cg = 0; cg < CG; cg++)
        acc[rg][cg] = __builtin_amdgcn_mfma_f32_16x16x32_bf16(ah[rg], bh[cg],
                                                              acc[rg][cg], 0, 0, 0);
#pragma unroll
    for (int rg = 0; rg < RG; rg++)
#pragma unroll
      for (int cg = 0; cg < CG; cg++)
        acc[rg][cg] = __builtin_amdgcn_mfma_f32_16x16x32_bf16(al[rg], bh[cg],
                                                              acc[rg][cg], 0, 0, 0);
#pragma unroll
    for (int rg = 0; rg < RG; rg++)
#pragma unroll
      for (int cg = 0; cg < CG; cg++)
        acc[rg][cg] = __builtin_amdgcn_mfma_f32_16x16x32_bf16(ah[rg], bl[cg],
                                                              acc[rg][cg], 0, 0, 0);
    if (kr < 3) {
#pragma unroll
      for (int rg = 0; rg < RG; rg++) { ah[rg] = nah[rg]; al[rg] = nal[rg]; }
#pragma unroll
      for (int cg = 0; cg < CG; cg++) { bh[cg] = nbh[cg]; bl[cg] = nbl[cg]; }
    }
  }

  // epilogue: scale by dinv[row], round to bf16, store
#pragma unroll
  for (int rg = 0; rg < RG; rg++) {
#pragma unroll
    for (int reg = 0; reg < 4; reg++) {
      const int row = row0 + rg * 16 + q * 4 + reg;
      if (row < NN) {
        const float dv = dinv[row];
#pragma unroll
        for (int cg = 0; cg < CG; cg++) {
          hs[(size_t)row * COUT + (cg0 + cg) * 16 + c] = bfr(acc[rg][cg][reg] * dv);
        }
      }
    }
  }
}

// ---------------- aggregation (bf16 gather, fp32 accumulate) ------------------

template <bool RELU>
__global__ __launch_bounds__(256) void k_agg128(const ushortT* __restrict__ hs,
                                                const int* __restrict__ rowptr,
                                                const int* __restrict__ col,
                                                const float* __restrict__ dinv,
                                                const float* __restrict__ bias,
                                                ushortT* __restrict__ A2) {
  const int gid = blockIdx.x * 256 + threadIdx.x;
  const int node = gid >> 6;  // one wave per node
  if (node >= NN) return;
  const int lane = threadIdx.x & 63;
  const int q = lane >> 4;          // quarter 0..3
  const int chb = (lane & 15) * 8;  // 8 channels per lane
  const int beg = rowptr[node];
  const int end = rowptr[node + 1];

  float a[8] = {};
  if (q == 0) {  // self-loop contribution
    const uint4 v = *reinterpret_cast<const uint4*>(hs + (long)node * 128 + chb);
    acc8(v, a);
  }

  int j = beg;
  if (j + 8 <= end) {
    int c0 = col[j + q];
    int c1 = col[j + 4 + q];
    while (true) {
      const uint4 v0 = *reinterpret_cast<const uint4*>(hs + (long)c0 * 128 + chb);
      const uint4 v1 = *reinterpret_cast<const uint4*>(hs + (long)c1 * 128 + chb);
      j += 8;
      const bool more = (j + 8 <= end);
      int n0, n1;
      if (more) { n0 = col[j + q]; n1 = col[j + 4 + q]; }
      acc8(v0, a);
      acc8(v1, a);
      if (!more) break;
      c0 = n0; c1 = n1;
    }
  }
  for (; j + 4 <= end; j += 4) {
    int c = col[j + q];
    const uint4 v = *reinterpret_cast<const uint4*>(hs + (long)c * 128 + chb);
    acc8(v, a);
  }
  {
    const int r = end - j;  // 0..3
    if (q < r) {
      int c = col[j + q];
      const uint4 v = *reinterpret_cast<const uint4*>(hs + (long)c * 128 + chb);
      acc8(v, a);
    }
  }

#pragma unroll
  for (int i = 0; i < 8; i++) a[i] += __shfl(a[i], lane ^ 32);
#pragma unroll
  for (int i = 0; i < 8; i++) a[i] += __shfl(a[i], lane ^ 16);

  if (q == 0) {
    const float di = dinv[node];
    const float4 b0 = *reinterpret_cast<const float4*>(bias + chb);
    const float4 b1 = *reinterpret_cast<const float4*>(bias + chb + 4);
    float o[8];
    o[0] = fmaf(a[0], di, b0.x); o[1] = fmaf(a[1], di, b0.y);
    o[2] = fmaf(a[2], di, b0.z); o[3] = fmaf(a[3], di, b0.w);
    o[4] = fmaf(a[4], di, b1.x); o[5] = fmaf(a[5], di, b1.y);
    o[6] = fmaf(a[6], di, b1.z); o[7] = fmaf(a[7], di, b1.w);
    if (RELU) {
#pragma unroll
      for (int i = 0; i < 8; i++) o[i] = fmaxf(o[i], 0.f);
    }
    uint4 H, L;
    split2(o[0], o[1], H.x, L.x);
    split2(o[2], o[3], H.y, L.y);
    split2(o[4], o[5], H.z, L.z);
    split2(o[6], o[7], H.w, L.w);
    *reinterpret_cast<uint4*>(A2 + (long)node * 256 + chb) = H;
    *reinterpret_cast<uint4*>(A2 + (long)node * 256 + 128 + chb) = L;
  }
}

__global__ __launch_bounds__(256) void k_agg64(const ushortT* __restrict__ hs,
                                               const int* __restrict__ rowptr,
                                               const int* __restrict__ col,
                                               const float* __restrict__ dinv,
                                               const float* __restrict__ bias,
                                               float* __restrict__ out) {
  const int gid = blockIdx.x * 256 + threadIdx.x;
  const int node = gid >> 6;
  if (node >= NN) return;
  const int lane = threadIdx.x & 63;
  const int o8 = lane >> 3;        // eighth 0..7
  const int chb = (lane & 7) * 8;  // 8 channels per lane
  const int beg = rowptr[node];
  const int end = rowptr[node + 1];

  float a[8] = {};
  if (o8 == 0) {  // self
    const uint4 v = *reinterpret_cast<const uint4*>(hs + (long)node * 64 + chb);
    acc8(v, a);
  }

  int j = beg;
  if (j + 16 <= end) {
    int c0 = col[j + o8];
    int c1 = col[j + 8 + o8];
    while (true) {
      const uint4 v0 = *reinterpret_cast<const uint4*>(hs + (long)c0 * 64 + chb);
      const uint4 v1 = *reinterpret_cast<const uint4*>(hs + (long)c1 * 64 + chb);
      j += 16;
      const bool more = (j + 16 <= end);
      int n0, n1;
      if (more) { n0 = col[j + o8]; n1 = col[j + 8 + o8]; }
      acc8(v0, a);
      acc8(v1, a);
      if (!more) break;
      c0 = n0; c1 = n1;
    }
  }
  for (; j + 8 <= end; j += 8) {
    int c = col[j + o8];
    const uint4 v = *reinterpret_cast<const uint4*>(hs + (long)c * 64 + chb);
    acc8(v, a);
  }
  {
    const int r = end - j;  // 0..7
    if (o8 < r) {
      int c = col[j + o8];
      const uint4 v = *reinterpret_cast<const uint4*>(hs + (long)c * 64 + chb);
      acc8(v, a);
    }
  }

#pragma unroll
  for (int i = 0; i < 8; i++) a[i] += __shfl(a[i], lane ^ 32);
#pragma unroll
  for (int i = 0; i < 8; i++) a[i] += __shfl(a[i], lane ^ 16);
#pragma unroll
  for (int i = 0; i < 8; i++) a[i] += __shfl(a[i], lane ^ 8);

  if (o8 == 0) {
    const float di = dinv[node];
    const float4 b0 = *reinterpret_cast<const float4*>(bias + chb);
    const float4 b1 = *reinterpret_cast<const float4*>(bias + chb + 4);
    float4 r0, r1;
    r0.x = fmaf(a[0], di, b0.x); r0.y = fmaf(a[1], di, b0.y);
    r0.z = fmaf(a[2], di, b0.z); r0.w = fmaf(a[3], di, b0.w);
    r1.x = fmaf(a[4], di, b1.x); r1.y = fmaf(a[5], di, b1.y);
    r1.z = fmaf(a[6], di, b1.z); r1.w = fmaf(a[7], di, b1.w);
    *reinterpret_cast<float4*>(out + (long)node * 64 + chb) = r0;
    *reinterpret_cast<float4*>(out + (long)node * 64 + chb + 4) = r1;
  }
}

// ---------------- launch ----------------

extern "C" void kernel_launch(void* const* d_in, const int* in_sizes, int n_in,
                              void* d_out, int out_size, void* d_ws, size_t ws_size,
                              hipStream_t stream) {
  const float* x  = (const float*)d_in[0];
  const int* ei   = (const int*)d_in[1];
  const float* W1 = (const float*)d_in[2];
  const float* b1 = (const float*)d_in[3];
  const float* W2 = (const float*)d_in[4];
  const float* b2 = (const float*)d_in[5];
  const float* W3 = (const float*)d_in[6];
  const float* b3 = (const float*)d_in[7];
  float* out = (float*)d_out;
  const int* srcp = ei;        // edge_index[0]
  const int* dstp = ei + NE;   // edge_index[1]

  char* wsb = (char*)d_ws;
  size_t off = 0;
  auto alloc = [&](size_t bytes) -> void* {
    void* p = wsb + off;
    off += (bytes + 255) & ~(size_t)255;
    return p;
  };
  ushortT* A2  = (ushortT*)alloc((size_t)MPAD * 256 * 2);   // [hi|lo] activations
  ushortT* hs  = (ushortT*)alloc((size_t)NN * 128 * 2);     // bf16 transform out
  int*   col    = (int*)alloc((size_t)NE * 4);
  int*   rowptr = (int*)alloc((size_t)(NN + 1) * 4);
  float* dinv   = (float*)alloc((size_t)NN * 4);
  int*   cursor = (int*)alloc((size_t)NBK * 4);
  ushortT* Bp1 = (ushortT*)alloc((size_t)32768 * 2);  // 8 seg x 8 cg x 512
  ushortT* Bp2 = (ushortT*)alloc((size_t)32768 * 2);
  ushortT* Bp3 = (ushortT*)alloc((size_t)16384 * 2);  // 8 seg x 4 cg x 512
  // pairArr (98*20480*8 = 16.05 MB) aliases hs (25.6 MB): build-only.
  ull* pairArr = (ull*)hs;
  (void)ws_size; (void)in_sizes; (void)n_in; (void)out_size;

  hipMemsetAsync(cursor, 0, (size_t)NBK * 4, stream);
  k_scatterpack<<<SCB + 320, 256, 0, stream>>>(srcp, dstp, cursor, pairArr,
                                               W1, W2, W3, Bp1, Bp2, Bp3);
  k_buildcsr<<<NBK, 256, 0, stream>>>(pairArr, cursor, dinv, rowptr, col);

  const int aggGrid = (NN * 64) / 256;  // 25000
  const int gemmGrid = MPAD / 128;      // 782

  // layer 1 (fused fp32 split — reads X directly)
  k_gemmM<128, true><<<gemmGrid, 256, 0, stream>>>(nullptr, x, Bp1, dinv, hs);
  k_agg128<true><<<aggGrid, 256, 0, stream>>>(hs, rowptr, col, dinv, b1, A2);
  // layer 2
  k_gemmM<128, false><<<gemmGrid, 256, 0, stream>>>(A2, nullptr, Bp2, dinv, hs);
  k_agg128<true><<<aggGrid, 256, 0, stream>>>(hs, rowptr, col, dinv, b2, A2);
  // layer 3 (128 -> 64, no relu)
  k_gemmM<64, false><<<gemmGrid, 256, 0, stream>>>(A2, nullptr, Bp3, dinv, hs);
  k_agg64<<<aggGrid, 256, 0, stream>>>(hs, rowptr, col, dinv, b3, out);
}

// Round 10
// 409.207 us; speedup vs baseline: 1.7023x; 1.0053x over previous
//
#include <hip/hip_runtime.h>

#define NN 100000
#define NE 1600000
#define NBK 98   // buckets of 1024 nodes
#define BSH 10   // bucket = dst >> 10
#define MPAD 100096  // NN padded to 128-row tiles (782*128)
#define SCB 391      // ceil(NE/4096) scatter blocks
#define CAP 20480    // padded slots per bucket (expected max ~16.8K)

typedef unsigned short ushortT;
typedef unsigned long long ull;
using sh8 = __attribute__((ext_vector_type(8))) short;   // 8 bf16 (4 VGPR) MFMA frag
using f4  = __attribute__((ext_vector_type(4))) float;   // MFMA accumulator

// ---------------- bf16 helpers ----------------

__device__ __forceinline__ unsigned short bfr(float f) {
  unsigned u = __float_as_uint(f);
  u += 0x7FFF + ((u >> 16) & 1);
  return (unsigned short)(u >> 16);
}
__device__ __forceinline__ float bf2f(unsigned short h) {
  return __uint_as_float(((unsigned)h) << 16);
}
__device__ __forceinline__ void split2(float a, float b, unsigned& H, unsigned& L) {
  unsigned short ha = bfr(a), hb = bfr(b);
  H = (unsigned)ha | ((unsigned)hb << 16);
  L = (unsigned)bfr(a - bf2f(ha)) | ((unsigned)bfr(b - bf2f(hb)) << 16);
}
__device__ __forceinline__ void acc8(const uint4 v, float* a) {
  a[0] += __uint_as_float(v.x << 16);
  a[1] += __uint_as_float(v.x & 0xFFFF0000u);
  a[2] += __uint_as_float(v.y << 16);
  a[3] += __uint_as_float(v.y & 0xFFFF0000u);
  a[4] += __uint_as_float(v.z << 16);
  a[5] += __uint_as_float(v.z & 0xFFFF0000u);
  a[6] += __uint_as_float(v.w << 16);
  a[7] += __uint_as_float(v.w & 0xFFFF0000u);
}
__device__ __forceinline__ sh8 hi8(const float4 a, const float4 b) {
  sh8 r;
  r[0] = (short)bfr(a.x); r[1] = (short)bfr(a.y);
  r[2] = (short)bfr(a.z); r[3] = (short)bfr(a.w);
  r[4] = (short)bfr(b.x); r[5] = (short)bfr(b.y);
  r[6] = (short)bfr(b.z); r[7] = (short)bfr(b.w);
  return r;
}
__device__ __forceinline__ sh8 lo8(const float4 a, const float4 b, const sh8 h) {
  sh8 r;
  r[0] = (short)bfr(a.x - bf2f((unsigned short)h[0]));
  r[1] = (short)bfr(a.y - bf2f((unsigned short)h[1]));
  r[2] = (short)bfr(a.z - bf2f((unsigned short)h[2]));
  r[3] = (short)bfr(a.w - bf2f((unsigned short)h[3]));
  r[4] = (short)bfr(b.x - bf2f((unsigned short)h[4]));
  r[5] = (short)bfr(b.y - bf2f((unsigned short)h[5]));
  r[6] = (short)bfr(b.z - bf2f((unsigned short)h[6]));
  r[7] = (short)bfr(b.w - bf2f((unsigned short)h[7]));
  return r;
}

// ---------------- W pack helper ----------------
// Bp[((ks*CG + g)*64 + lane)*8 + j]; k=(ks&3)*32+(lane>>4)*8+j, n=g*16+(lane&15)
// hi for ks<4, lo residue for ks>=4.

template <int COUT>
__device__ __forceinline__ void packone(const float* __restrict__ W,
                                        ushortT* __restrict__ Bp, int i) {
  const int j = i & 7;
  const int l = (i >> 3) & 63;
  const int rest = i >> 9;
  const int g = rest % (COUT / 16);
  const int ks = rest / (COUT / 16);
  const int k = (ks & 3) * 32 + (l >> 4) * 8 + j;
  const int n = g * 16 + (l & 15);
  const float v = W[k * COUT + n];
  const unsigned short h = bfr(v);
  Bp[i] = (ks < 4) ? h : bfr(v - bf2f(h));
}

// ---------------- fused scatter (padded buckets) + weight pack ---------------

__global__ __launch_bounds__(256) void k_scatterpack(
    const int* __restrict__ src, const int* __restrict__ dst,
    int* __restrict__ cursor, ull* __restrict__ pairArr,
    const float* __restrict__ W1, const float* __restrict__ W2,
    const float* __restrict__ W3, ushortT* __restrict__ Bp1,
    ushortT* __restrict__ Bp2, ushortT* __restrict__ Bp3) {
  if (blockIdx.x >= SCB) {
    const int i = (blockIdx.x - SCB) * 256 + threadIdx.x;  // 0..81919
    if (i < 32768) packone<128>(W1, Bp1, i);
    else if (i < 65536) packone<128>(W2, Bp2, i - 32768);
    else packone<64>(W3, Bp3, i - 65536);
    return;
  }
  __shared__ int lcnt[NBK];
  __shared__ int lbase[NBK];
  __shared__ int lrank[NBK];
  __shared__ int bbase[NBK];
  __shared__ ull sorted[4096];
  __shared__ int target[4096];
  const int t = threadIdx.x;
  for (int i = t; i < NBK; i += 256) { lcnt[i] = 0; lrank[i] = 0; }
  __syncthreads();
  const int base = blockIdx.x * 4096;
  int rs[16], rd[16];
#pragma unroll
  for (int q = 0; q < 16; q++) {
    int e = base + t + 256 * q;
    rs[q] = (e < NE) ? src[e] : -1;
    rd[q] = (e < NE) ? dst[e] : -1;
    if (rd[q] >= 0) atomicAdd(&lcnt[rd[q] >> BSH], 1);
  }
  __syncthreads();
  if (t == 0) {
    int run = 0;
    for (int i = 0; i < NBK; i++) { lbase[i] = run; run += lcnt[i]; }
  }
  __syncthreads();
  if (t < NBK && lcnt[t] > 0) bbase[t] = atomicAdd(&cursor[t], lcnt[t]);
  __syncthreads();
#pragma unroll
  for (int q = 0; q < 16; q++) {
    if (rd[q] >= 0) {
      int b = rd[q] >> BSH;
      int r = atomicAdd(&lrank[b], 1);
      int slot = lbase[b] + r;
      sorted[slot] = ((ull)(unsigned)rs[q] << 32) | (unsigned)rd[q];
      target[slot] = b * CAP + bbase[b] + r;  // padded-bucket placement
    }
  }
  __syncthreads();
  const int n = min(4096, NE - base);
  for (int s = t; s < n; s += 256) pairArr[target[s]] = sorted[s];
}

// ---------------- CSR build: one block per bucket ----------------------------

__global__ __launch_bounds__(256) void k_buildcsr(const ull* __restrict__ pairArr,
                                                  const int* __restrict__ cnt,
                                                  float* __restrict__ dinv,
                                                  int* __restrict__ rowptr,
                                                  int* __restrict__ col) {
  __shared__ int lc[1024];
  __shared__ int sd[256];
  __shared__ int bc[NBK];
  __shared__ int ebegS;
  const int t = threadIdx.x;
  const int b = blockIdx.x;
  const int n0 = b << BSH;
  if (t < NBK) bc[t] = cnt[t];
  for (int i = t; i < 1024; i += 256) lc[i] = 0;
  __syncthreads();
  if (t == 0) {
    int run = 0;
    for (int i = 0; i < b; i++) run += bc[i];
    ebegS = run;
  }
  __syncthreads();
  const int ebeg = ebegS;
  const int myCnt = bc[b];
  const ull* pb = pairArr + (size_t)b * CAP;
  for (int i = t; i < myCnt; i += 256)
    atomicAdd(&lc[(int)(unsigned)(pb[i] & 0xffffffffULL) - n0], 1);
  __syncthreads();
  const int v0 = lc[t * 4], v1 = lc[t * 4 + 1], v2 = lc[t * 4 + 2], v3 = lc[t * 4 + 3];
  const int s = v0 + v1 + v2 + v3;
  sd[t] = s;
  __syncthreads();
  for (int off = 1; off < 256; off <<= 1) {
    int x = (t >= off) ? sd[t - off] : 0;
    __syncthreads();
    sd[t] += x;
    __syncthreads();
  }
  const int run = sd[t] - s;  // exclusive within bucket
  const int c0 = run, c1 = run + v0, c2 = c1 + v1, c3 = c2 + v2;
  lc[t * 4] = c0; lc[t * 4 + 1] = c1; lc[t * 4 + 2] = c2; lc[t * 4 + 3] = c3;
  const int cnts[4] = {v0, v1, v2, v3};
  const int curs[4] = {c0, c1, c2, c3};
#pragma unroll
  for (int i = 0; i < 4; i++) {
    int node = n0 + t * 4 + i;
    if (node < NN) {
      rowptr[node] = ebeg + curs[i];
      dinv[node] = rsqrtf(1.0f + (float)cnts[i]);  // self-loop => deg >= 1
    }
  }
  if (b == 0 && t == 0) rowptr[NN] = NE;
  __syncthreads();
  for (int i = t; i < myCnt; i += 256) {
    ull p = pb[i];
    int d = (int)(unsigned)(p & 0xffffffffULL);
    int srcv = (int)(unsigned)(p >> 32);
    int pos = atomicAdd(&lc[d - n0], 1);
    col[ebeg + pos] = srcv;
  }
}

// ---------------- MFMA GEMM: hs = bf16( X @ W * dinv ), split-bf16 3-pass ----
// RG=2 (32 rows/wave): ~145 VGPR -> 3+ blocks/CU (vs RG=4's 2) for latency
// hiding; CG=4 keeps B loads L1-resident. COUT=128 grid = MPAD/64.
// Frag layouts: A m=lane&15,k=quad*8+j [m120]; B n=lane&15 [m97];
// C/D col=lane&15,row=quad*4+reg [m89].

template <int COUT, bool FUSED>
__global__ __launch_bounds__(256) void k_gemmM(const ushortT* __restrict__ A2,
                                               const float* __restrict__ X,
                                               const ushortT* __restrict__ Bp,
                                               const float* __restrict__ dinv,
                                               ushortT* __restrict__ hs) {
  constexpr int CGALL = COUT / 16;              // 8 or 4
  constexpr int RG = 2;                         // row-groups per wave (32 rows)
  constexpr int CG = 4;                         // col-groups per wave (64 cols)
  const int w = threadIdx.x >> 6;
  const int lane = threadIdx.x & 63;
  const int q = lane >> 4;
  const int c = lane & 15;
  int row0, cg0;
  if (COUT == 128) {
    row0 = blockIdx.x * 64 + (w & 1) * 32;     // block: 64 rows x 128 cols
    cg0 = (w >> 1) * 4;
  } else {
    row0 = blockIdx.x * 128 + w * 32;          // block: 128 rows x 64 cols
    cg0 = 0;
  }

  const ushortT* ap[RG];
  const float* xp[RG];
#pragma unroll
  for (int rg = 0; rg < RG; rg++) {
    const int row = row0 + rg * 16 + c;
    if (FUSED) xp[rg] = X + (size_t)min(row, NN - 1) * 128 + q * 8;
    else ap[rg] = A2 + (size_t)row * 256 + q * 8;
  }
  const ushortT* bp0 = Bp + (size_t)lane * 8;

  f4 acc[RG][CG];
#pragma unroll
  for (int i = 0; i < RG; i++)
#pragma unroll
    for (int j = 0; j < CG; j++) acc[i][j] = (f4){0.f, 0.f, 0.f, 0.f};

  sh8 ah[RG], al[RG], bh[CG], bl[CG];
  sh8 nah[RG], nal[RG], nbh[CG], nbl[CG];

  auto loadA = [&](int kr, sh8 (&h)[RG], sh8 (&l)[RG]) {
#pragma unroll
    for (int rg = 0; rg < RG; rg++) {
      if (FUSED) {
        const float4 x0 = *reinterpret_cast<const float4*>(xp[rg] + kr * 32);
        const float4 x1 = *reinterpret_cast<const float4*>(xp[rg] + kr * 32 + 4);
        h[rg] = hi8(x0, x1);
        l[rg] = lo8(x0, x1, h[rg]);
      } else {
        h[rg] = *reinterpret_cast<const sh8*>(ap[rg] + kr * 32);
        l[rg] = *reinterpret_cast<const sh8*>(ap[rg] + 128 + kr * 32);
      }
    }
  };
  auto loadB = [&](int kr, sh8 (&h)[CG], sh8 (&l)[CG]) {
#pragma unroll
    for (int cg = 0; cg < CG; cg++) {
      h[cg] = *reinterpret_cast<const sh8*>(bp0 + (size_t)(kr * CGALL + cg0 + cg) * 512);
      l[cg] = *reinterpret_cast<const sh8*>(bp0 + (size_t)((4 + kr) * CGALL + cg0 + cg) * 512);
    }
  };

  loadA(0, ah, al);
  loadB(0, bh, bl);
#pragma unroll
  for (int kr = 0; kr < 4; kr++) {
    if (kr < 3) {
      loadA(kr + 1, nah, nal);
      loadB(kr + 1, nbh, nbl);
    }
#pragma unroll
    for (int rg = 0; rg < RG; rg++)
#pragma unroll
      for (int cg = 0; cg < CG; cg++)
        acc[rg][cg] = __builtin_amdgcn_mfma_f32_16x16x32_bf16(ah[rg], bh[cg],
                                                              acc[rg][cg], 0, 0, 0);
#pragma unroll
    for (int rg = 0; rg < RG; rg++)
#pragma unroll
      for (int cg = 0; cg < CG; cg++)
        acc[rg][cg] = __builtin_amdgcn_mfma_f32_16x16x32_bf16(al[rg], bh[cg],
                                                              acc[rg][cg], 0, 0, 0);
#pragma unroll
    for (int rg = 0; rg < RG; rg++)
#pragma unroll
      for (int cg = 0; cg < CG; cg++)
        acc[rg][cg] = __builtin_amdgcn_mfma_f32_16x16x32_bf16(ah[rg], bl[cg],
                                                              acc[rg][cg], 0, 0, 0);
    if (kr < 3) {
#pragma unroll
      for (int rg = 0; rg < RG; rg++) { ah[rg] = nah[rg]; al[rg] = nal[rg]; }
#pragma unroll
      for (int cg = 0; cg < CG; cg++) { bh[cg] = nbh[cg]; bl[cg] = nbl[cg]; }
    }
  }

  // epilogue: scale by dinv[row], round to bf16, store
#pragma unroll
  for (int rg = 0; rg < RG; rg++) {
#pragma unroll
    for (int reg = 0; reg < 4; reg++) {
      const int row = row0 + rg * 16 + q * 4 + reg;
      if (row < NN) {
        const float dv = dinv[row];
#pragma unroll
        for (int cg = 0; cg < CG; cg++) {
          hs[(size_t)row * COUT + (cg0 + cg) * 16 + c] = bfr(acc[rg][cg][reg] * dv);
        }
      }
    }
  }
}

// ---------------- aggregation (bf16 gather, fp32 accumulate) ------------------

template <bool RELU>
__global__ __launch_bounds__(256) void k_agg128(const ushortT* __restrict__ hs,
                                                const int* __restrict__ rowptr,
                                                const int* __restrict__ col,
                                                const float* __restrict__ dinv,
                                                const float* __restrict__ bias,
                                                ushortT* __restrict__ A2) {
  const int gid = blockIdx.x * 256 + threadIdx.x;
  const int node = gid >> 6;  // one wave per node
  if (node >= NN) return;
  const int lane = threadIdx.x & 63;
  const int q = lane >> 4;          // quarter 0..3
  const int chb = (lane & 15) * 8;  // 8 channels per lane
  const int beg = rowptr[node];
  const int end = rowptr[node + 1];

  float a[8] = {};
  if (q == 0) {  // self-loop contribution
    const uint4 v = *reinterpret_cast<const uint4*>(hs + (long)node * 128 + chb);
    acc8(v, a);
  }

  int j = beg;
  if (j + 8 <= end) {
    int c0 = col[j + q];
    int c1 = col[j + 4 + q];
    while (true) {
      const uint4 v0 = *reinterpret_cast<const uint4*>(hs + (long)c0 * 128 + chb);
      const uint4 v1 = *reinterpret_cast<const uint4*>(hs + (long)c1 * 128 + chb);
      j += 8;
      const bool more = (j + 8 <= end);
      int n0, n1;
      if (more) { n0 = col[j + q]; n1 = col[j + 4 + q]; }
      acc8(v0, a);
      acc8(v1, a);
      if (!more) break;
      c0 = n0; c1 = n1;
    }
  }
  for (; j + 4 <= end; j += 4) {
    int c = col[j + q];
    const uint4 v = *reinterpret_cast<const uint4*>(hs + (long)c * 128 + chb);
    acc8(v, a);
  }
  {
    const int r = end - j;  // 0..3
    if (q < r) {
      int c = col[j + q];
      const uint4 v = *reinterpret_cast<const uint4*>(hs + (long)c * 128 + chb);
      acc8(v, a);
    }
  }

#pragma unroll
  for (int i = 0; i < 8; i++) a[i] += __shfl(a[i], lane ^ 32);
#pragma unroll
  for (int i = 0; i < 8; i++) a[i] += __shfl(a[i], lane ^ 16);

  if (q == 0) {
    const float di = dinv[node];
    const float4 b0 = *reinterpret_cast<const float4*>(bias + chb);
    const float4 b1 = *reinterpret_cast<const float4*>(bias + chb + 4);
    float o[8];
    o[0] = fmaf(a[0], di, b0.x); o[1] = fmaf(a[1], di, b0.y);
    o[2] = fmaf(a[2], di, b0.z); o[3] = fmaf(a[3], di, b0.w);
    o[4] = fmaf(a[4], di, b1.x); o[5] = fmaf(a[5], di, b1.y);
    o[6] = fmaf(a[6], di, b1.z); o[7] = fmaf(a[7], di, b1.w);
    if (RELU) {
#pragma unroll
      for (int i = 0; i < 8; i++) o[i] = fmaxf(o[i], 0.f);
    }
    uint4 H, L;
    split2(o[0], o[1], H.x, L.x);
    split2(o[2], o[3], H.y, L.y);
    split2(o[4], o[5], H.z, L.z);
    split2(o[6], o[7], H.w, L.w);
    *reinterpret_cast<uint4*>(A2 + (long)node * 256 + chb) = H;
    *reinterpret_cast<uint4*>(A2 + (long)node * 256 + 128 + chb) = L;
  }
}

__global__ __launch_bounds__(256) void k_agg64(const ushortT* __restrict__ hs,
                                               const int* __restrict__ rowptr,
                                               const int* __restrict__ col,
                                               const float* __restrict__ dinv,
                                               const float* __restrict__ bias,
                                               float* __restrict__ out) {
  const int gid = blockIdx.x * 256 + threadIdx.x;
  const int node = gid >> 6;
  if (node >= NN) return;
  const int lane = threadIdx.x & 63;
  const int o8 = lane >> 3;        // eighth 0..7
  const int chb = (lane & 7) * 8;  // 8 channels per lane
  const int beg = rowptr[node];
  const int end = rowptr[node + 1];

  float a[8] = {};
  if (o8 == 0) {  // self
    const uint4 v = *reinterpret_cast<const uint4*>(hs + (long)node * 64 + chb);
    acc8(v, a);
  }

  int j = beg;
  if (j + 16 <= end) {
    int c0 = col[j + o8];
    int c1 = col[j + 8 + o8];
    while (true) {
      const uint4 v0 = *reinterpret_cast<const uint4*>(hs + (long)c0 * 64 + chb);
      const uint4 v1 = *reinterpret_cast<const uint4*>(hs + (long)c1 * 64 + chb);
      j += 16;
      const bool more = (j + 16 <= end);
      int n0, n1;
      if (more) { n0 = col[j + o8]; n1 = col[j + 8 + o8]; }
      acc8(v0, a);
      acc8(v1, a);
      if (!more) break;
      c0 = n0; c1 = n1;
    }
  }
  for (; j + 8 <= end; j += 8) {
    int c = col[j + o8];
    const uint4 v = *reinterpret_cast<const uint4*>(hs + (long)c * 64 + chb);
    acc8(v, a);
  }
  {
    const int r = end - j;  // 0..7
    if (o8 < r) {
      int c = col[j + o8];
      const uint4 v = *reinterpret_cast<const uint4*>(hs + (long)c * 64 + chb);
      acc8(v, a);
    }
  }

#pragma unroll
  for (int i = 0; i < 8; i++) a[i] += __shfl(a[i], lane ^ 32);
#pragma unroll
  for (int i = 0; i < 8; i++) a[i] += __shfl(a[i], lane ^ 16);
#pragma unroll
  for (int i = 0; i < 8; i++) a[i] += __shfl(a[i], lane ^ 8);

  if (o8 == 0) {
    const float di = dinv[node];
    const float4 b0 = *reinterpret_cast<const float4*>(bias + chb);
    const float4 b1 = *reinterpret_cast<const float4*>(bias + chb + 4);
    float4 r0, r1;
    r0.x = fmaf(a[0], di, b0.x); r0.y = fmaf(a[1], di, b0.y);
    r0.z = fmaf(a[2], di, b0.z); r0.w = fmaf(a[3], di, b0.w);
    r1.x = fmaf(a[4], di, b1.x); r1.y = fmaf(a[5], di, b1.y);
    r1.z = fmaf(a[6], di, b1.z); r1.w = fmaf(a[7], di, b1.w);
    *reinterpret_cast<float4*>(out + (long)node * 64 + chb) = r0;
    *reinterpret_cast<float4*>(out + (long)node * 64 + chb + 4) = r1;
  }
}

// ---------------- launch ----------------

extern "C" void kernel_launch(void* const* d_in, const int* in_sizes, int n_in,
                              void* d_out, int out_size, void* d_ws, size_t ws_size,
                              hipStream_t stream) {
  const float* x  = (const float*)d_in[0];
  const int* ei   = (const int*)d_in[1];
  const float* W1 = (const float*)d_in[2];
  const float* b1 = (const float*)d_in[3];
  const float* W2 = (const float*)d_in[4];
  const float* b2 = (const float*)d_in[5];
  const float* W3 = (const float*)d_in[6];
  const float* b3 = (const float*)d_in[7];
  float* out = (float*)d_out;
  const int* srcp = ei;        // edge_index[0]
  const int* dstp = ei + NE;   // edge_index[1]

  char* wsb = (char*)d_ws;
  size_t off = 0;
  auto alloc = [&](size_t bytes) -> void* {
    void* p = wsb + off;
    off += (bytes + 255) & ~(size_t)255;
    return p;
  };
  ushortT* A2  = (ushortT*)alloc((size_t)MPAD * 256 * 2);   // [hi|lo] activations
  ushortT* hs  = (ushortT*)alloc((size_t)NN * 128 * 2);     // bf16 transform out
  int*   col    = (int*)alloc((size_t)NE * 4);
  int*   rowptr = (int*)alloc((size_t)(NN + 1) * 4);
  float* dinv   = (float*)alloc((size_t)NN * 4);
  int*   cursor = (int*)alloc((size_t)NBK * 4);
  ushortT* Bp1 = (ushortT*)alloc((size_t)32768 * 2);  // 8 seg x 8 cg x 512
  ushortT* Bp2 = (ushortT*)alloc((size_t)32768 * 2);
  ushortT* Bp3 = (ushortT*)alloc((size_t)16384 * 2);  // 8 seg x 4 cg x 512
  // pairArr (98*20480*8 = 16.05 MB) aliases hs (25.6 MB): build-only.
  ull* pairArr = (ull*)hs;
  (void)ws_size; (void)in_sizes; (void)n_in; (void)out_size;

  hipMemsetAsync(cursor, 0, (size_t)NBK * 4, stream);
  k_scatterpack<<<SCB + 320, 256, 0, stream>>>(srcp, dstp, cursor, pairArr,
                                               W1, W2, W3, Bp1, Bp2, Bp3);
  k_buildcsr<<<NBK, 256, 0, stream>>>(pairArr, cursor, dinv, rowptr, col);

  const int aggGrid = (NN * 64) / 256;   // 25000
  const int gemmGrid128 = MPAD / 64;     // 1564 (64-row blocks)
  const int gemmGrid64 = MPAD / 128;     // 782 (128-row blocks)

  // layer 1 (fused fp32 split — reads X directly)
  k_gemmM<128, true><<<gemmGrid128, 256, 0, stream>>>(nullptr, x, Bp1, dinv, hs);
  k_agg128<true><<<aggGrid, 256, 0, stream>>>(hs, rowptr, col, dinv, b1, A2);
  // layer 2
  k_gemmM<128, false><<<gemmGrid128, 256, 0, stream>>>(A2, nullptr, Bp2, dinv, hs);
  k_agg128<true><<<aggGrid, 256, 0, stream>>>(hs, rowptr, col, dinv, b2, A2);
  // layer 3 (128 -> 64, no relu)
  k_gemmM<64, false><<<gemmGrid64, 256, 0, stream>>>(A2, nullptr, Bp3, dinv, hs);
  k_agg64<<<aggGrid, 256, 0, stream>>>(hs, rowptr, col, dinv, b3, out);
}

// Round 11
// 372.131 us; speedup vs baseline: 1.8719x; 1.0996x over previous
//
#include <hip/hip_runtime.h>

#define NN 100000
#define NE 1600000
#define NBK 98   // buckets of 1024 nodes
#define BSH 10   // bucket = dst >> 10
#define MPAD 100096  // NN padded to 128-row tiles (782*128)
#define SCB 391      // ceil(NE/4096) scatter blocks
#define CAP 20480    // padded slots per bucket (expected max ~16.8K)

typedef unsigned short ushortT;
typedef unsigned long long ull;
using sh8 = __attribute__((ext_vector_type(8))) short;   // 8 bf16 (4 VGPR) MFMA frag
using f4  = __attribute__((ext_vector_type(4))) float;   // MFMA accumulator

// ---------------- bf16 helpers ----------------

__device__ __forceinline__ unsigned short bfr(float f) {
  unsigned u = __float_as_uint(f);
  u += 0x7FFF + ((u >> 16) & 1);
  return (unsigned short)(u >> 16);
}
__device__ __forceinline__ float bf2f(unsigned short h) {
  return __uint_as_float(((unsigned)h) << 16);
}
__device__ __forceinline__ void acc8(const uint4 v, float* a) {
  a[0] += __uint_as_float(v.x << 16);
  a[1] += __uint_as_float(v.x & 0xFFFF0000u);
  a[2] += __uint_as_float(v.y << 16);
  a[3] += __uint_as_float(v.y & 0xFFFF0000u);
  a[4] += __uint_as_float(v.z << 16);
  a[5] += __uint_as_float(v.z & 0xFFFF0000u);
  a[6] += __uint_as_float(v.w << 16);
  a[7] += __uint_as_float(v.w & 0xFFFF0000u);
}
__device__ __forceinline__ sh8 hi8(const float4 a, const float4 b) {
  sh8 r;
  r[0] = (short)bfr(a.x); r[1] = (short)bfr(a.y);
  r[2] = (short)bfr(a.z); r[3] = (short)bfr(a.w);
  r[4] = (short)bfr(b.x); r[5] = (short)bfr(b.y);
  r[6] = (short)bfr(b.z); r[7] = (short)bfr(b.w);
  return r;
}

// ---------------- W pack helper ----------------
// Bp[((ks*CG + g)*64 + lane)*8 + j]; k=(ks&3)*32+(lane>>4)*8+j, n=g*16+(lane&15)
// hi for ks<4, lo residue for ks>=4.  (W stays split: keeps the weight error
// term at 2^-18 while activations carry the accepted 2^-9.)

template <int COUT>
__device__ __forceinline__ void packone(const float* __restrict__ W,
                                        ushortT* __restrict__ Bp, int i) {
  const int j = i & 7;
  const int l = (i >> 3) & 63;
  const int rest = i >> 9;
  const int g = rest % (COUT / 16);
  const int ks = rest / (COUT / 16);
  const int k = (ks & 3) * 32 + (l >> 4) * 8 + j;
  const int n = g * 16 + (l & 15);
  const float v = W[k * COUT + n];
  const unsigned short h = bfr(v);
  Bp[i] = (ks < 4) ? h : bfr(v - bf2f(h));
}

// ---------------- fused scatter (padded buckets) + weight pack ---------------

__global__ __launch_bounds__(256) void k_scatterpack(
    const int* __restrict__ src, const int* __restrict__ dst,
    int* __restrict__ cursor, ull* __restrict__ pairArr,
    const float* __restrict__ W1, const float* __restrict__ W2,
    const float* __restrict__ W3, ushortT* __restrict__ Bp1,
    ushortT* __restrict__ Bp2, ushortT* __restrict__ Bp3) {
  if (blockIdx.x >= SCB) {
    const int i = (blockIdx.x - SCB) * 256 + threadIdx.x;  // 0..81919
    if (i < 32768) packone<128>(W1, Bp1, i);
    else if (i < 65536) packone<128>(W2, Bp2, i - 32768);
    else packone<64>(W3, Bp3, i - 65536);
    return;
  }
  __shared__ int lcnt[NBK];
  __shared__ int lbase[NBK];
  __shared__ int lrank[NBK];
  __shared__ int bbase[NBK];
  __shared__ ull sorted[4096];
  __shared__ int target[4096];
  const int t = threadIdx.x;
  for (int i = t; i < NBK; i += 256) { lcnt[i] = 0; lrank[i] = 0; }
  __syncthreads();
  const int base = blockIdx.x * 4096;
  int rs[16], rd[16];
#pragma unroll
  for (int q = 0; q < 16; q++) {
    int e = base + t + 256 * q;
    rs[q] = (e < NE) ? src[e] : -1;
    rd[q] = (e < NE) ? dst[e] : -1;
    if (rd[q] >= 0) atomicAdd(&lcnt[rd[q] >> BSH], 1);
  }
  __syncthreads();
  if (t == 0) {
    int run = 0;
    for (int i = 0; i < NBK; i++) { lbase[i] = run; run += lcnt[i]; }
  }
  __syncthreads();
  if (t < NBK && lcnt[t] > 0) bbase[t] = atomicAdd(&cursor[t], lcnt[t]);
  __syncthreads();
#pragma unroll
  for (int q = 0; q < 16; q++) {
    if (rd[q] >= 0) {
      int b = rd[q] >> BSH;
      int r = atomicAdd(&lrank[b], 1);
      int slot = lbase[b] + r;
      sorted[slot] = ((ull)(unsigned)rs[q] << 32) | (unsigned)rd[q];
      target[slot] = b * CAP + bbase[b] + r;  // padded-bucket placement
    }
  }
  __syncthreads();
  const int n = min(4096, NE - base);
  for (int s = t; s < n; s += 256) pairArr[target[s]] = sorted[s];
}

// ---------------- CSR build: one block (1024 thr) per bucket -----------------
// thread t owns node n0+t. Count via LDS atomics, 1024-wide Hillis-Steele
// scan for intra-bucket offsets, then col fill via LDS cursors.

__global__ __launch_bounds__(1024) void k_buildcsr(const ull* __restrict__ pairArr,
                                                   const int* __restrict__ cnt,
                                                   float* __restrict__ dinv,
                                                   int* __restrict__ rowptr,
                                                   int* __restrict__ col) {
  __shared__ int lc[1024];
  __shared__ int sd[1024];
  __shared__ int bc[NBK];
  __shared__ int ebegS;
  const int t = threadIdx.x;
  const int b = blockIdx.x;
  const int n0 = b << BSH;
  if (t < NBK) bc[t] = cnt[t];
  lc[t] = 0;
  __syncthreads();
  if (t == 0) {
    int run = 0;
    for (int i = 0; i < b; i++) run += bc[i];
    ebegS = run;
  }
  __syncthreads();
  const int ebeg = ebegS;
  const int myCnt = bc[b];
  const ull* pb = pairArr + (size_t)b * CAP;
  for (int i = t; i < myCnt; i += 1024)
    atomicAdd(&lc[(int)(unsigned)(pb[i] & 0xffffffffULL) - n0], 1);
  __syncthreads();
  const int v = lc[t];
  sd[t] = v;
  __syncthreads();
  for (int off = 1; off < 1024; off <<= 1) {
    int x = (t >= off) ? sd[t - off] : 0;
    __syncthreads();
    sd[t] += x;
    __syncthreads();
  }
  const int excl = sd[t] - v;  // exclusive within bucket
  lc[t] = excl;                // cursor
  const int node = n0 + t;
  if (node < NN) {
    rowptr[node] = ebeg + excl;
    dinv[node] = rsqrtf(1.0f + (float)v);  // self-loop => deg >= 1
  }
  if (b == 0 && t == 0) rowptr[NN] = NE;
  __syncthreads();
  for (int i = t; i < myCnt; i += 1024) {
    ull p = pb[i];
    int d = (int)(unsigned)(p & 0xffffffffULL);
    int srcv = (int)(unsigned)(p >> 32);
    int pos = atomicAdd(&lc[d - n0], 1);
    col[ebeg + pos] = srcv;
  }
}

// ---------------- MFMA GEMM: hs = bf16( A @ W * dinv ) -----------------------
// A = bf16 activations (layer1: fp32 X rounded in-reg). W split hi/lo, 2-pass
// per 32-wide K chunk: a@Whi + a@Wlo. RG=2, CG=4. Frag layouts: A m=lane&15,
// k=quad*8+j [m120]; B n=lane&15 [m97]; C/D col=lane&15,row=quad*4+reg [m89].

template <int COUT, bool FUSED>
__global__ __launch_bounds__(256) void k_gemmM(const ushortT* __restrict__ A,
                                               const float* __restrict__ X,
                                               const ushortT* __restrict__ Bp,
                                               const float* __restrict__ dinv,
                                               ushortT* __restrict__ hs) {
  constexpr int CGALL = COUT / 16;              // 8 or 4
  constexpr int RG = 2;                         // row-groups per wave (32 rows)
  constexpr int CG = 4;                         // col-groups per wave (64 cols)
  const int w = threadIdx.x >> 6;
  const int lane = threadIdx.x & 63;
  const int q = lane >> 4;
  const int c = lane & 15;
  int row0, cg0;
  if (COUT == 128) {
    row0 = blockIdx.x * 64 + (w & 1) * 32;     // block: 64 rows x 128 cols
    cg0 = (w >> 1) * 4;
  } else {
    row0 = blockIdx.x * 128 + w * 32;          // block: 128 rows x 64 cols
    cg0 = 0;
  }

  const ushortT* ap[RG];
  const float* xp[RG];
#pragma unroll
  for (int rg = 0; rg < RG; rg++) {
    const int row = row0 + rg * 16 + c;
    if (FUSED) xp[rg] = X + (size_t)min(row, NN - 1) * 128 + q * 8;
    else ap[rg] = A + (size_t)row * 128 + q * 8;
  }
  const ushortT* bp0 = Bp + (size_t)lane * 8;

  f4 acc[RG][CG];
#pragma unroll
  for (int i = 0; i < RG; i++)
#pragma unroll
    for (int j = 0; j < CG; j++) acc[i][j] = (f4){0.f, 0.f, 0.f, 0.f};

  sh8 ah[RG], bh[CG], bl[CG];
  sh8 nah[RG], nbh[CG], nbl[CG];

  auto loadA = [&](int kr, sh8 (&h)[RG]) {
#pragma unroll
    for (int rg = 0; rg < RG; rg++) {
      if (FUSED) {
        const float4 x0 = *reinterpret_cast<const float4*>(xp[rg] + kr * 32);
        const float4 x1 = *reinterpret_cast<const float4*>(xp[rg] + kr * 32 + 4);
        h[rg] = hi8(x0, x1);
      } else {
        h[rg] = *reinterpret_cast<const sh8*>(ap[rg] + kr * 32);
      }
    }
  };
  auto loadB = [&](int kr, sh8 (&h)[CG], sh8 (&l)[CG]) {
#pragma unroll
    for (int cg = 0; cg < CG; cg++) {
      h[cg] = *reinterpret_cast<const sh8*>(bp0 + (size_t)(kr * CGALL + cg0 + cg) * 512);
      l[cg] = *reinterpret_cast<const sh8*>(bp0 + (size_t)((4 + kr) * CGALL + cg0 + cg) * 512);
    }
  };

  loadA(0, ah);
  loadB(0, bh, bl);
#pragma unroll
  for (int kr = 0; kr < 4; kr++) {
    if (kr < 3) {
      loadA(kr + 1, nah);
      loadB(kr + 1, nbh, nbl);
    }
#pragma unroll
    for (int rg = 0; rg < RG; rg++)
#pragma unroll
      for (int cg = 0; cg < CG; cg++)
        acc[rg][cg] = __builtin_amdgcn_mfma_f32_16x16x32_bf16(ah[rg], bh[cg],
                                                              acc[rg][cg], 0, 0, 0);
#pragma unroll
    for (int rg = 0; rg < RG; rg++)
#pragma unroll
      for (int cg = 0; cg < CG; cg++)
        acc[rg][cg] = __builtin_amdgcn_mfma_f32_16x16x32_bf16(ah[rg], bl[cg],
                                                              acc[rg][cg], 0, 0, 0);
    if (kr < 3) {
#pragma unroll
      for (int rg = 0; rg < RG; rg++) ah[rg] = nah[rg];
#pragma unroll
      for (int cg = 0; cg < CG; cg++) { bh[cg] = nbh[cg]; bl[cg] = nbl[cg]; }
    }
  }

  // epilogue: scale by dinv[row], round to bf16, store
#pragma unroll
  for (int rg = 0; rg < RG; rg++) {
#pragma unroll
    for (int reg = 0; reg < 4; reg++) {
      const int row = row0 + rg * 16 + q * 4 + reg;
      if (row < NN) {
        const float dv = dinv[row];
#pragma unroll
        for (int cg = 0; cg < CG; cg++) {
          hs[(size_t)row * COUT + (cg0 + cg) * 16 + c] = bfr(acc[rg][cg][reg] * dv);
        }
      }
    }
  }
}

// ---------------- aggregation (bf16 gather, fp32 accumulate) ------------------
// Output: bf16 activations (16 B per q==0 lane) — halves the write traffic.

template <bool RELU>
__global__ __launch_bounds__(256) void k_agg128(const ushortT* __restrict__ hs,
                                                const int* __restrict__ rowptr,
                                                const int* __restrict__ col,
                                                const float* __restrict__ dinv,
                                                const float* __restrict__ bias,
                                                ushortT* __restrict__ A) {
  const int gid = blockIdx.x * 256 + threadIdx.x;
  const int node = gid >> 6;  // one wave per node
  if (node >= NN) return;
  const int lane = threadIdx.x & 63;
  const int q = lane >> 4;          // quarter 0..3
  const int chb = (lane & 15) * 8;  // 8 channels per lane
  const int beg = rowptr[node];
  const int end = rowptr[node + 1];

  float a[8] = {};
  if (q == 0) {  // self-loop contribution
    const uint4 v = *reinterpret_cast<const uint4*>(hs + (long)node * 128 + chb);
    acc8(v, a);
  }

  int j = beg;
  if (j + 8 <= end) {
    int c0 = col[j + q];
    int c1 = col[j + 4 + q];
    while (true) {
      const uint4 v0 = *reinterpret_cast<const uint4*>(hs + (long)c0 * 128 + chb);
      const uint4 v1 = *reinterpret_cast<const uint4*>(hs + (long)c1 * 128 + chb);
      j += 8;
      const bool more = (j + 8 <= end);
      int n0, n1;
      if (more) { n0 = col[j + q]; n1 = col[j + 4 + q]; }
      acc8(v0, a);
      acc8(v1, a);
      if (!more) break;
      c0 = n0; c1 = n1;
    }
  }
  for (; j + 4 <= end; j += 4) {
    int c = col[j + q];
    const uint4 v = *reinterpret_cast<const uint4*>(hs + (long)c * 128 + chb);
    acc8(v, a);
  }
  {
    const int r = end - j;  // 0..3
    if (q < r) {
      int c = col[j + q];
      const uint4 v = *reinterpret_cast<const uint4*>(hs + (long)c * 128 + chb);
      acc8(v, a);
    }
  }

#pragma unroll
  for (int i = 0; i < 8; i++) a[i] += __shfl(a[i], lane ^ 32);
#pragma unroll
  for (int i = 0; i < 8; i++) a[i] += __shfl(a[i], lane ^ 16);

  if (q == 0) {
    const float di = dinv[node];
    const float4 b0 = *reinterpret_cast<const float4*>(bias + chb);
    const float4 b1 = *reinterpret_cast<const float4*>(bias + chb + 4);
    float o[8];
    o[0] = fmaf(a[0], di, b0.x); o[1] = fmaf(a[1], di, b0.y);
    o[2] = fmaf(a[2], di, b0.z); o[3] = fmaf(a[3], di, b0.w);
    o[4] = fmaf(a[4], di, b1.x); o[5] = fmaf(a[5], di, b1.y);
    o[6] = fmaf(a[6], di, b1.z); o[7] = fmaf(a[7], di, b1.w);
    if (RELU) {
#pragma unroll
      for (int i = 0; i < 8; i++) o[i] = fmaxf(o[i], 0.f);
    }
    uint4 H;
    H.x = (unsigned)bfr(o[0]) | ((unsigned)bfr(o[1]) << 16);
    H.y = (unsigned)bfr(o[2]) | ((unsigned)bfr(o[3]) << 16);
    H.z = (unsigned)bfr(o[4]) | ((unsigned)bfr(o[5]) << 16);
    H.w = (unsigned)bfr(o[6]) | ((unsigned)bfr(o[7]) << 16);
    *reinterpret_cast<uint4*>(A + (long)node * 128 + chb) = H;
  }
}

__global__ __launch_bounds__(256) void k_agg64(const ushortT* __restrict__ hs,
                                               const int* __restrict__ rowptr,
                                               const int* __restrict__ col,
                                               const float* __restrict__ dinv,
                                               const float* __restrict__ bias,
                                               float* __restrict__ out) {
  const int gid = blockIdx.x * 256 + threadIdx.x;
  const int node = gid >> 6;
  if (node >= NN) return;
  const int lane = threadIdx.x & 63;
  const int o8 = lane >> 3;        // eighth 0..7
  const int chb = (lane & 7) * 8;  // 8 channels per lane
  const int beg = rowptr[node];
  const int end = rowptr[node + 1];

  float a[8] = {};
  if (o8 == 0) {  // self
    const uint4 v = *reinterpret_cast<const uint4*>(hs + (long)node * 64 + chb);
    acc8(v, a);
  }

  int j = beg;
  if (j + 16 <= end) {
    int c0 = col[j + o8];
    int c1 = col[j + 8 + o8];
    while (true) {
      const uint4 v0 = *reinterpret_cast<const uint4*>(hs + (long)c0 * 64 + chb);
      const uint4 v1 = *reinterpret_cast<const uint4*>(hs + (long)c1 * 64 + chb);
      j += 16;
      const bool more = (j + 16 <= end);
      int n0, n1;
      if (more) { n0 = col[j + o8]; n1 = col[j + 8 + o8]; }
      acc8(v0, a);
      acc8(v1, a);
      if (!more) break;
      c0 = n0; c1 = n1;
    }
  }
  for (; j + 8 <= end; j += 8) {
    int c = col[j + o8];
    const uint4 v = *reinterpret_cast<const uint4*>(hs + (long)c * 64 + chb);
    acc8(v, a);
  }
  {
    const int r = end - j;  // 0..7
    if (o8 < r) {
      int c = col[j + o8];
      const uint4 v = *reinterpret_cast<const uint4*>(hs + (long)c * 64 + chb);
      acc8(v, a);
    }
  }

#pragma unroll
  for (int i = 0; i < 8; i++) a[i] += __shfl(a[i], lane ^ 32);
#pragma unroll
  for (int i = 0; i < 8; i++) a[i] += __shfl(a[i], lane ^ 16);
#pragma unroll
  for (int i = 0; i < 8; i++) a[i] += __shfl(a[i], lane ^ 8);

  if (o8 == 0) {
    const float di = dinv[node];
    const float4 b0 = *reinterpret_cast<const float4*>(bias + chb);
    const float4 b1 = *reinterpret_cast<const float4*>(bias + chb + 4);
    float4 r0, r1;
    r0.x = fmaf(a[0], di, b0.x); r0.y = fmaf(a[1], di, b0.y);
    r0.z = fmaf(a[2], di, b0.z); r0.w = fmaf(a[3], di, b0.w);
    r1.x = fmaf(a[4], di, b1.x); r1.y = fmaf(a[5], di, b1.y);
    r1.z = fmaf(a[6], di, b1.z); r1.w = fmaf(a[7], di, b1.w);
    *reinterpret_cast<float4*>(out + (long)node * 64 + chb) = r0;
    *reinterpret_cast<float4*>(out + (long)node * 64 + chb + 4) = r1;
  }
}

// ---------------- launch ----------------

extern "C" void kernel_launch(void* const* d_in, const int* in_sizes, int n_in,
                              void* d_out, int out_size, void* d_ws, size_t ws_size,
                              hipStream_t stream) {
  const float* x  = (const float*)d_in[0];
  const int* ei   = (const int*)d_in[1];
  const float* W1 = (const float*)d_in[2];
  const float* b1 = (const float*)d_in[3];
  const float* W2 = (const float*)d_in[4];
  const float* b2 = (const float*)d_in[5];
  const float* W3 = (const float*)d_in[6];
  const float* b3 = (const float*)d_in[7];
  float* out = (float*)d_out;
  const int* srcp = ei;        // edge_index[0]
  const int* dstp = ei + NE;   // edge_index[1]

  char* wsb = (char*)d_ws;
  size_t off = 0;
  auto alloc = [&](size_t bytes) -> void* {
    void* p = wsb + off;
    off += (bytes + 255) & ~(size_t)255;
    return p;
  };
  ushortT* A   = (ushortT*)alloc((size_t)MPAD * 128 * 2);   // bf16 activations
  ushortT* hs  = (ushortT*)alloc((size_t)NN * 128 * 2);     // bf16 transform out
  int*   col    = (int*)alloc((size_t)NE * 4);
  int*   rowptr = (int*)alloc((size_t)(NN + 1) * 4);
  float* dinv   = (float*)alloc((size_t)NN * 4);
  int*   cursor = (int*)alloc((size_t)NBK * 4);
  ushortT* Bp1 = (ushortT*)alloc((size_t)32768 * 2);  // 8 seg x 8 cg x 512
  ushortT* Bp2 = (ushortT*)alloc((size_t)32768 * 2);
  ushortT* Bp3 = (ushortT*)alloc((size_t)16384 * 2);  // 8 seg x 4 cg x 512
  // pairArr (98*20480*8 = 16.05 MB) aliases hs (25.6 MB): build-only.
  ull* pairArr = (ull*)hs;
  (void)ws_size; (void)in_sizes; (void)n_in; (void)out_size;

  hipMemsetAsync(cursor, 0, (size_t)NBK * 4, stream);
  k_scatterpack<<<SCB + 320, 256, 0, stream>>>(srcp, dstp, cursor, pairArr,
                                               W1, W2, W3, Bp1, Bp2, Bp3);
  k_buildcsr<<<NBK, 1024, 0, stream>>>(pairArr, cursor, dinv, rowptr, col);

  const int aggGrid = (NN * 64) / 256;   // 25000
  const int gemmGrid128 = MPAD / 64;     // 1564 (64-row blocks)
  const int gemmGrid64 = MPAD / 128;     // 782 (128-row blocks)

  // layer 1 (fused — reads fp32 X directly, rounds to bf16 in-reg)
  k_gemmM<128, true><<<gemmGrid128, 256, 0, stream>>>(nullptr, x, Bp1, dinv, hs);
  k_agg128<true><<<aggGrid, 256, 0, stream>>>(hs, rowptr, col, dinv, b1, A);
  // layer 2
  k_gemmM<128, false><<<gemmGrid128, 256, 0, stream>>>(A, nullptr, Bp2, dinv, hs);
  k_agg128<true><<<aggGrid, 256, 0, stream>>>(hs, rowptr, col, dinv, b2, A);
  // layer 3 (128 -> 64, no relu)
  k_gemmM<64, false><<<gemmGrid64, 256, 0, stream>>>(A, nullptr, Bp3, dinv, hs);
  k_agg64<<<aggGrid, 256, 0, stream>>>(hs, rowptr, col, dinv, b3, out);
}